// Round 15
// baseline (5234.699 us; speedup 1.0000x reference)
//
#include <hip/hip_runtime.h>

#define N_NODES 131072
#define N_EDGES 524288
#define CCH 256
#define N_GRAPHS_ 2048
#define SEQ 64
#define LAYERS 6

typedef unsigned short US;
typedef __attribute__((ext_vector_type(8))) short v8s;           // MFMA bf16 frag
typedef __attribute__((ext_vector_type(8))) unsigned short v8us; // 16B ushort vector
typedef __attribute__((ext_vector_type(4))) float v4f;           // MFMA f32 acc

__device__ __forceinline__ float b2f(US u) { return __uint_as_float(((unsigned)u) << 16); }
__device__ __forceinline__ US f2b(float f) {
    unsigned u = __float_as_uint(f);
    return (US)((u + 0x7fff + ((u >> 16) & 1)) >> 16);   // RNE
}
__device__ __forceinline__ void gload16(const US* g, US* l) {
    __builtin_amdgcn_global_load_lds(
        (const __attribute__((address_space(1))) unsigned int*)g,
        (__attribute__((address_space(3))) unsigned int*)l, 16, 0, 0);
}

// cross-kernel state — referenced ONLY inside device code (never from host!)
__device__ float g_stats[512];
__device__ float g_aff1[512];
__device__ float g_aff2[512];
__device__ float g_aff3[512];
__device__ float g_pe[40];
__device__ float g_peaff[40];
__device__ US    g_wt[6 * 655360];          // per-layer transposed bf16 weights
__device__ int   g_csr[N_EDGES];            // per-graph dst-sorted edges: srcLocal | attr<<6
__device__ int   g_off[N_GRAPHS_ * 65];     // per-graph CSR offsets

// ---------------------------------------------------------------- weight transpose f32[K][C] -> bf16[C][K]
__global__ __launch_bounds__(256) void wt_k(const float* __restrict__ cw1, const float* __restrict__ cw2,
                                            const float* __restrict__ aiw, const float* __restrict__ aow,
                                            const float* __restrict__ mw1, const float* __restrict__ mw2) {
    __shared__ float t[64][65];
    int b = blockIdx.x;
    int l = b / 160, r = b % 160;
    const float* src; int ldw, ldk, ctiles; size_t doff;
    if (r < 16)      { src = cw1 + (size_t)l * 65536;  ldw = 256; ldk = 256; ctiles = 4;  doff = 0;      }
    else if (r < 32) { src = cw2 + (size_t)l * 65536;  ldw = 256; ldk = 256; ctiles = 4;  doff = 65536;  r -= 16; }
    else if (r < 80) { src = aiw + (size_t)l * 196608; ldw = 768; ldk = 256; ctiles = 12; doff = 131072; r -= 32; }
    else if (r < 96) { src = aow + (size_t)l * 65536;  ldw = 256; ldk = 256; ctiles = 4;  doff = 327680; r -= 80; }
    else if (r < 128){ src = mw1 + (size_t)l * 131072; ldw = 512; ldk = 256; ctiles = 8;  doff = 393216; r -= 96; }
    else             { src = mw2 + (size_t)l * 131072; ldw = 256; ldk = 512; ctiles = 4;  doff = 524288; r -= 128; }
    int kt = r / ctiles, ct = r % ctiles;
    int k0 = kt * 64, c0 = ct * 64;
    US* dst = g_wt + (size_t)l * 655360 + doff;
    int tid = threadIdx.x;
    int rr = tid >> 4, c4 = (tid & 15) * 4;
    #pragma unroll
    for (int j = 0; j < 4; j++) {
        float4 v = *(const float4*)(src + (size_t)(k0 + rr + j * 16) * ldw + c0 + c4);
        t[rr + j * 16][c4 + 0] = v.x; t[rr + j * 16][c4 + 1] = v.y;
        t[rr + j * 16][c4 + 2] = v.z; t[rr + j * 16][c4 + 3] = v.w;
    }
    __syncthreads();
    #pragma unroll
    for (int j = 0; j < 4; j++) {
        int crow = rr + j * 16;
        ushort4 o;
        o.x = f2b(t[c4 + 0][crow]); o.y = f2b(t[c4 + 1][crow]);
        o.z = f2b(t[c4 + 2][crow]); o.w = f2b(t[c4 + 3][crow]);
        *(ushort4*)(dst + (size_t)(c0 + crow) * ldk + k0 + c4) = o;
    }
}

// ---------------------------------------------------------------- CSR build (once per launch)
__global__ __launch_bounds__(256) void csr_k(const int* __restrict__ ei,
                                             const int* __restrict__ attr) {
    __shared__ int deg[64], off[65];
    int g = blockIdx.x, tid = threadIdx.x;
    if (tid < 64) deg[tid] = 0;
    __syncthreads();
    int e = g * 256 + tid;
    int d = ei[N_EDGES + e] - g * 64;
    int slot = atomicAdd(&deg[d], 1);
    __syncthreads();
    if (tid == 0) {
        off[0] = 0;
        for (int i = 0; i < 64; i++) off[i + 1] = off[i] + deg[i];
    }
    __syncthreads();
    g_csr[g * 256 + off[d] + slot] = (ei[e] - g * 64) | (attr[e] << 6);
    if (tid < 65) g_off[g * 65 + tid] = off[tid];
}

// ---------------------------------------------------------------- pe stats (2-stage)
__global__ __launch_bounds__(256) void pe_part_k(const float* __restrict__ pe) {
    __shared__ float red[240], red2[240];
    int b = blockIdx.x, tid = threadIdx.x;
    float s = 0.f, s2 = 0.f;
    if (tid < 240) {
        int ch = tid % 20, sub = tid / 20;
        size_t r0 = (size_t)b * 512;
        for (int r = sub; r < 512; r += 12) {
            float v = pe[(r0 + r) * 20 + ch];
            s += v; s2 += v * v;
        }
        red[tid] = s; red2[tid] = s2;
    }
    __syncthreads();
    if (tid < 20) {
        float ts = 0.f, ts2 = 0.f;
        #pragma unroll
        for (int sub = 0; sub < 12; sub++) { ts += red[sub * 20 + tid]; ts2 += red2[sub * 20 + tid]; }
        atomicAdd(&g_pe[tid], ts);
        atomicAdd(&g_pe[20 + tid], ts2);
    }
}

__global__ __launch_bounds__(64) void pe_fin_k(const float* __restrict__ g,
                                               const float* __restrict__ b) {
    int t = threadIdx.x;
    if (t < 20) {
        float mean = g_pe[t] / (float)N_NODES;
        float var  = g_pe[20 + t] / (float)N_NODES - mean * mean;
        float a = g[t] * rsqrtf(var + 1e-5f);
        g_peaff[t] = a;
        g_peaff[20 + t] = b[t] - mean * a;
        g_pe[t] = 0.f;          // re-zero for deterministic replay
        g_pe[20 + t] = 0.f;
    }
}

// ---------------------------------------------------------------- embed
__global__ __launch_bounds__(256) void embed_k(const int* __restrict__ x,
                                               const float* __restrict__ pe,
                                               const float* __restrict__ node_emb,
                                               const float* __restrict__ plw,
                                               const float* __restrict__ plb,
                                               US* __restrict__ h) {
    int n = blockIdx.x;
    int tid = threadIdx.x;
    int xi = x[n];
    float v;
    if (tid < 192) {
        v = node_emb[xi * 192 + tid];
    } else {
        int j = tid - 192;
        float s = plb[j];
        #pragma unroll
        for (int k = 0; k < 20; k++) {
            float p = pe[(size_t)n * 20 + k] * g_peaff[k] + g_peaff[20 + k];
            s += p * plw[k * 64 + j];
        }
        v = s;
    }
    h[(size_t)n * CCH + tid] = f2b(v);
}

// ---------------------------------------------------------------- edge aggregation: CSR, no atomics
// useAff: first apply h' = aff3(h) in place (block owns its graph's rows; gathers use LDS tile)
__global__ __launch_bounds__(256) void aggr_z_k(US* __restrict__ h,
                                                const float* __restrict__ eemb,
                                                US* __restrict__ z, int useAff) {
    __shared__ US ht[64 * 264];
    __shared__ float em[4 * 260];
    __shared__ int off[65], ce[256];
    int g = blockIdx.x, tid = threadIdx.x;
    for (int v = tid; v < 2048; v += 256) {
        int row = v >> 5, seg = (v & 31) * 8;
        v8us hv = *(const v8us*)(h + (size_t)(g * 64 + row) * 256 + seg);
        if (useAff) {
            v8us o;
            #pragma unroll
            for (int j = 0; j < 8; j++)
                o[j] = f2b(b2f(hv[j]) * g_aff3[seg + j] + g_aff3[CCH + seg + j]);
            hv = o;
            *(v8us*)(h + (size_t)(g * 64 + row) * 256 + seg) = hv;   // normalized h in place
        }
        *(v8us*)&ht[row * 264 + seg] = hv;
    }
    for (int i = tid; i < 1024; i += 256)
        em[(i >> 8) * 260 + (i & 255)] = eemb[(i >> 8) * 256 + (i & 255)];
    ce[tid] = g_csr[g * 256 + tid];
    if (tid < 65) off[tid] = g_off[g * 65 + tid];
    __syncthreads();

    int dst = tid >> 2, cq = (tid & 3) * 4;
    float acc[64];
    #pragma unroll
    for (int i = 0; i < 64; i++) acc[i] = 0.f;
    int e1 = off[dst + 1];
    for (int e = off[dst]; e < e1; e++) {
        int val = ce[e];
        int src = val & 63, a = (val >> 6) & 3;
        #pragma unroll
        for (int i = 0; i < 16; i++) {
            int c = cq + i * 16;
            ushort4 hv = *(ushort4*)&ht[src * 264 + c];
            float4 ev = *(float4*)&em[a * 260 + c];
            acc[i * 4 + 0] += fmaxf(b2f(hv.x) + ev.x, 0.f);
            acc[i * 4 + 1] += fmaxf(b2f(hv.y) + ev.y, 0.f);
            acc[i * 4 + 2] += fmaxf(b2f(hv.z) + ev.z, 0.f);
            acc[i * 4 + 3] += fmaxf(b2f(hv.w) + ev.w, 0.f);
        }
    }
    US* zp = z + (size_t)(g * 64 + dst) * 256;
    #pragma unroll
    for (int i = 0; i < 16; i++) {
        int c = cq + i * 16;
        ushort4 hv = *(ushort4*)&ht[dst * 264 + c];
        ushort4 o;
        o.x = f2b(b2f(hv.x) + acc[i * 4 + 0]);
        o.y = f2b(b2f(hv.y) + acc[i * 4 + 1]);
        o.z = f2b(b2f(hv.z) + acc[i * 4 + 2]);
        o.w = f2b(b2f(hv.w) + acc[i * 4 + 3]);
        *(ushort4*)(zp + c) = o;
    }
}

// ---------------------------------------------------------------- MFMA bf16 GEMM  (BM=64, EXACT round-10 version)
template<int NG, bool STATS>
__global__ __launch_bounds__(256, 4) void gemm_mfma_k(const US* __restrict__ A,
                                                      size_t woff, int ldk,
                                                      int w0, int w1, int w2, int w3,
                                                      const float* __restrict__ bias,
                                                      const US* __restrict__ res,
                                                      US* __restrict__ Y, int mode) {
    const US* __restrict__ Wt = g_wt + woff;
    __shared__ __align__(16) char smem[8192 + 2 * NG * 4096];
    US* As0 = (US*)smem;
    US* As1 = As0 + 2048;
    US* Bs0 = (US*)(smem + 8192);
    US* Bs1 = Bs0 + NG * 2048;
    float* Es = (float*)smem;
    const int NW = NG * 64 + 4;

    int tid = threadIdx.x;
    int bid = blockIdx.x;
    int swz = (bid & 7) * ((int)gridDim.x >> 3) + (bid >> 3);
    size_t row0 = (size_t)swz * 64;
    int w = tid >> 6, l = tid & 63;
    int li = l & 15, hi = l >> 4;
    int sl = hi ^ ((li >> 1) & 3);
    int sr = l >> 2, ss = l & 3;

    int a_off = (w * 16 + li) * 32 + sl * 8;

    v4f acc[NG * 4];
    #pragma unroll
    for (int t = 0; t < NG * 4; t++) acc[t] = (v4f){0.f, 0.f, 0.f, 0.f};

    int ar = w * 16 + sr;
    int akg = (ss ^ ((ar >> 1) & 3)) * 8;
    const US* asrc = A + (row0 + ar) * 256 + akg;

    auto stage = [&](int kc, US* Asb, US* Bsb) {
        int k0 = kc * 32;
        gload16(asrc + k0, Asb + w * 512);
        #pragma unroll
        for (int j = 0; j < NG; j++) {
            int cu = (j * 4 + w) * 16 + sr;
            int grp = cu >> 6;
            int wb = (grp == 0) ? w0 : (grp == 1) ? w1 : (grp == 2) ? w2 : w3;
            int kg = (ss ^ ((cu >> 1) & 3)) * 8;
            gload16(Wt + (size_t)(wb + (cu & 63)) * ldk + k0 + kg,
                    Bsb + (j * 4 + w) * 512);
        }
    };

    stage(0, As0, Bs0);
    __syncthreads();
    for (int kc = 0; kc < 8; kc++) {
        US* Asc = (kc & 1) ? As1 : As0;
        US* Bsc = (kc & 1) ? Bs1 : Bs0;
        if (kc < 7) stage(kc + 1, (kc & 1) ? As0 : As1, (kc & 1) ? Bs0 : Bs1);
        v8s a0 = *(v8s*)(Asc + a_off);
        #pragma unroll
        for (int t = 0; t < NG * 4; t++) {
            v8s bf = *(v8s*)(Bsc + (t * 16 + li) * 32 + sl * 8);
            acc[t] = __builtin_amdgcn_mfma_f32_16x16x32_bf16(a0, bf, acc[t], 0, 0, 0);
        }
        __syncthreads();
    }

    int er_f = tid >> 3;
    int lcb = (tid & 7) * 8;
    float csum = 0.f, csum2 = 0.f;
    #pragma unroll
    for (int p = 0; p < 2; p++) {
        if ((w >> 1) == p) {
            int er0 = (w & 1) * 16 + hi * 4;
            #pragma unroll
            for (int t = 0; t < NG * 4; t++) {
                int grp = t >> 2;
                int wb = (grp == 0) ? w0 : (grp == 1) ? w1 : (grp == 2) ? w2 : w3;
                float bv = bias ? bias[wb + (t & 3) * 16 + li] : 0.f;
                #pragma unroll
                for (int r = 0; r < 4; r++) {
                    float v = acc[t][r] + bv;
                    if (mode == 1) v = fmaxf(v, 0.f);
                    Es[(er0 + r) * NW + t * 16 + li] = v;
                }
            }
        }
        __syncthreads();
        size_t gr = row0 + p * 32 + er_f;
        #pragma unroll
        for (int s = 0; s < NG; s++) {
            int c = s * 64 + lcb;
            float vs[8];
            #pragma unroll
            for (int j = 0; j < 8; j++) vs[j] = Es[er_f * NW + c + j];
            if (mode == 2) {
                v8us rv = *(const v8us*)(res + gr * 256 + c);
                #pragma unroll
                for (int j = 0; j < 8; j++) vs[j] += b2f(rv[j]);
            }
            v8us yv;
            #pragma unroll
            for (int j = 0; j < 8; j++) yv[j] = f2b(vs[j]);
            *(v8us*)(Y + gr * 256 + c) = yv;
            if constexpr (STATS) {
                #pragma unroll
                for (int j = 0; j < 8; j++) Es[er_f * NW + c + j] = vs[j];
            }
        }
        if constexpr (STATS) {
            __syncthreads();
            if (tid < NG * 64) {
                float s1 = 0.f, s2 = 0.f;
                #pragma unroll 8
                for (int r2 = 0; r2 < 32; r2++) {
                    float vv = Es[r2 * NW + tid];
                    s1 += vv; s2 += vv * vv;
                }
                csum += s1; csum2 += s2;
            }
        }
        __syncthreads();
    }
    if constexpr (STATS) {
        if (tid < NG * 64) {
            atomicAdd(&g_stats[tid], csum);
            atomicAdd(&g_stats[CCH + tid], csum2);
        }
    }
}

// ---------------------------------------------------------------- FUSED chained GEMM: Y = relu(X@W1+b1)@W2 + b2 + res
// COMB=false: X = A (gload_lds), res = res arg.
// COMB=true:  X = res = aff1(A=C) + aff2(H2=h) computed on the fly (combine fused).
// NH 256-wide t-chunks. Stats always accumulated into g_stats.
template<int NH, bool COMB>
__global__ __launch_bounds__(256, 2) void mlp_fused_k(const US* __restrict__ A,
                                                      const US* __restrict__ H2,
                                                      size_t woff1, const float* __restrict__ bias1,
                                                      size_t woff2, int ldk2,
                                                      const float* __restrict__ bias2,
                                                      const US* __restrict__ res,
                                                      US* __restrict__ Y) {
    const US* __restrict__ W1t = g_wt + woff1;
    const US* __restrict__ W2t = g_wt + woff2;
    __shared__ __align__(16) char smem[73728];
    US* As0 = (US*)smem;
    US* As1 = (US*)(smem + 4096);
    US* Bs0 = (US*)(smem + 8192);
    US* Bs1 = (US*)(smem + 24576);
    float* Es = (float*)smem;
    US* Ts = (US*)(smem + 40960);

    int tid = threadIdx.x;
    int bid = blockIdx.x;
    int swz = (bid & 7) * ((int)gridDim.x >> 3) + (bid >> 3);
    size_t row0 = (size_t)swz * 64;
    int w = tid >> 6, l = tid & 63;
    int li = l & 15, hi = l >> 4;
    int sl = hi ^ ((li >> 1) & 3);
    int sr = l >> 2, ss = l & 3;

    int a_off = (w * 16 + li) * 32 + sl * 8;

    v4f accY[16];
    #pragma unroll
    for (int t = 0; t < 16; t++) accY[t] = (v4f){0.f, 0.f, 0.f, 0.f};

    int ar = w * 16 + sr;
    int akg = (ss ^ ((ar >> 1) & 3)) * 8;
    const US* asrc = A + (row0 + ar) * 256 + akg;
    const US* hsrc = COMB ? (H2 + (row0 + ar) * 256 + akg) : nullptr;

    #pragma unroll
    for (int q = 0; q < NH; q++) {
        v4f accT[16];
        #pragma unroll
        for (int t = 0; t < 16; t++) accT[t] = (v4f){0.f, 0.f, 0.f, 0.f};

        auto stageA = [&](int kc, US* Asb, US* Bsb) {
            int k0 = kc * 32;
            if constexpr (COMB) {
                int cidx = k0 + akg;
                v8us cv = *(const v8us*)(asrc + k0);
                v8us hv = *(const v8us*)(hsrc + k0);
                v8us t;
                #pragma unroll
                for (int j = 0; j < 8; j++) {
                    float v = b2f(cv[j]) * g_aff1[cidx + j] + g_aff1[CCH + cidx + j] +
                              b2f(hv[j]) * g_aff2[cidx + j] + g_aff2[CCH + cidx + j];
                    t[j] = f2b(v);
                }
                *(v8us*)&Asb[w * 512 + l * 8] = t;
            } else {
                gload16(asrc + k0, Asb + w * 512);
            }
            #pragma unroll
            for (int j = 0; j < 4; j++) {
                int cu = (j * 4 + w) * 16 + sr;
                int kg = (ss ^ ((cu >> 1) & 3)) * 8;
                gload16(W1t + (size_t)(q * 256 + cu) * 256 + k0 + kg,
                        Bsb + (j * 4 + w) * 512);
            }
        };
        stageA(0, As0, Bs0);
        __syncthreads();
        for (int kc = 0; kc < 8; kc++) {
            US* Asc = (kc & 1) ? As1 : As0;
            US* Bsc = (kc & 1) ? Bs1 : Bs0;
            if (kc < 7) stageA(kc + 1, (kc & 1) ? As0 : As1, (kc & 1) ? Bs0 : Bs1);
            v8s a0 = *(v8s*)(Asc + a_off);
            #pragma unroll
            for (int t = 0; t < 16; t++) {
                v8s bf = *(v8s*)(Bsc + (t * 16 + li) * 32 + sl * 8);
                accT[t] = __builtin_amdgcn_mfma_f32_16x16x32_bf16(a0, bf, accT[t], 0, 0, 0);
            }
            __syncthreads();
        }
        // ---- t -> Ts via Es transpose (bias + relu + bf16 round) ----
        #pragma unroll
        for (int p = 0; p < 2; p++) {
            if ((w >> 1) == p) {
                int er0 = (w & 1) * 16 + hi * 4;
                #pragma unroll
                for (int t = 0; t < 16; t++) {
                    float bv = bias1[q * 256 + t * 16 + li];
                    #pragma unroll
                    for (int r = 0; r < 4; r++)
                        Es[(er0 + r) * 260 + t * 16 + li] = fmaxf(accT[t][r] + bv, 0.f);
                }
            }
            __syncthreads();
            {
                int er = tid >> 3, lcb = (tid & 7) * 8;
                int rowL = p * 32 + er;
                int rsw = (rowL >> 1) & 3;
                #pragma unroll
                for (int s = 0; s < 4; s++) {
                    int col = s * 64 + lcb;
                    v8us tv;
                    #pragma unroll
                    for (int j = 0; j < 8; j++) tv[j] = f2b(Es[er * 260 + col + j]);
                    int chunk = col >> 5, slot = ((col >> 3) & 3) ^ rsw;
                    *(v8us*)&Ts[chunk * 2048 + rowL * 32 + slot * 8] = tv;
                }
            }
            __syncthreads();
        }
        // ---- phase B: accY += t @ W2[q*256 + k][:] ----
        auto stageB = [&](int kc, US* Bsb) {
            int k0 = q * 256 + kc * 32;
            #pragma unroll
            for (int j = 0; j < 4; j++) {
                int cu = (j * 4 + w) * 16 + sr;
                int kg = (ss ^ ((cu >> 1) & 3)) * 8;
                gload16(W2t + (size_t)cu * ldk2 + k0 + kg, Bsb + (j * 4 + w) * 512);
            }
        };
        stageB(0, Bs0);
        __syncthreads();
        for (int kc = 0; kc < 8; kc++) {
            US* Bsc = (kc & 1) ? Bs1 : Bs0;
            if (kc < 7) stageB(kc + 1, (kc & 1) ? Bs0 : Bs1);
            v8s a0 = *(v8s*)(Ts + kc * 2048 + a_off);
            #pragma unroll
            for (int t = 0; t < 16; t++) {
                v8s bf = *(v8s*)(Bsc + (t * 16 + li) * 32 + sl * 8);
                accY[t] = __builtin_amdgcn_mfma_f32_16x16x32_bf16(a0, bf, accY[t], 0, 0, 0);
            }
            __syncthreads();
        }
    }

    // ---- final epilogue: bias2 + res(/combine) + stats -> Y ----
    int er_f = tid >> 3;
    int lcb = (tid & 7) * 8;
    float csum = 0.f, csum2 = 0.f;
    #pragma unroll
    for (int p = 0; p < 2; p++) {
        if ((w >> 1) == p) {
            int er0 = (w & 1) * 16 + hi * 4;
            #pragma unroll
            for (int t = 0; t < 16; t++) {
                float bv = bias2[t * 16 + li];
                #pragma unroll
                for (int r = 0; r < 4; r++)
                    Es[(er0 + r) * 260 + t * 16 + li] = accY[t][r] + bv;
            }
        }
        __syncthreads();
        size_t gr = row0 + p * 32 + er_f;
        #pragma unroll
        for (int s = 0; s < 4; s++) {
            int c = s * 64 + lcb;
            float vs[8];
            #pragma unroll
            for (int j = 0; j < 8; j++) vs[j] = Es[er_f * 260 + c + j];
            if constexpr (COMB) {
                v8us c8 = *(const v8us*)(A + gr * 256 + c);
                v8us h8 = *(const v8us*)(H2 + gr * 256 + c);
                #pragma unroll
                for (int j = 0; j < 8; j++) {
                    float cb = b2f(c8[j]) * g_aff1[c + j] + g_aff1[CCH + c + j] +
                               b2f(h8[j]) * g_aff2[c + j] + g_aff2[CCH + c + j];
                    vs[j] += b2f(f2b(cb));
                }
            } else {
                v8us rv = *(const v8us*)(res + gr * 256 + c);
                #pragma unroll
                for (int j = 0; j < 8; j++) vs[j] += b2f(rv[j]);
            }
            v8us yv;
            #pragma unroll
            for (int j = 0; j < 8; j++) yv[j] = f2b(vs[j]);
            *(v8us*)(Y + gr * 256 + c) = yv;
            #pragma unroll
            for (int j = 0; j < 8; j++) Es[er_f * 260 + c + j] = vs[j];
        }
        __syncthreads();
        {
            float s1 = 0.f, s2 = 0.f;
            #pragma unroll 8
            for (int r2 = 0; r2 < 32; r2++) {
                float vv = Es[r2 * 260 + tid];
                s1 += vv; s2 += vv * vv;
            }
            csum += s1; csum2 += s2;
        }
        __syncthreads();
    }
    atomicAdd(&g_stats[tid], csum);
    atomicAdd(&g_stats[CCH + tid], csum2);
}

// ---------------------------------------------------------------- MFMA attention: 1 wave = (graph, head)  [R10]
__global__ __launch_bounds__(64) void attn_k(const US* __restrict__ qkv,
                                             US* __restrict__ o) {
    __shared__ __align__(16) US Ps[64 * 72];
    __shared__ __align__(16) US Vt[64 * 72];
    int g = blockIdx.x, l = threadIdx.x;
    int li = l & 15, hi8 = (l >> 4) * 8, hi4 = (l >> 4) * 4;
    const US* base = qkv + (size_t)g * 64 * 256;

    {
        v8us vv[8];
        #pragma unroll
        for (int jv = 0; jv < 8; jv++)
            vv[jv] = *(const v8us*)(base + l * 256 + 128 + jv * 8);
        #pragma unroll
        for (int jv = 0; jv < 8; jv++)
            #pragma unroll
            for (int e = 0; e < 8; e++)
                Vt[(jv * 8 + e) * 72 + l] = vv[jv][e];
    }

    v8s Qf[4][2], Kf[4][2];
    #pragma unroll
    for (int t = 0; t < 4; t++)
        #pragma unroll
        for (int ds = 0; ds < 2; ds++) {
            Qf[t][ds] = *(const v8s*)(base + (t * 16 + li) * 256 + ds * 32 + hi8);
            Kf[t][ds] = *(const v8s*)(base + (t * 16 + li) * 256 + 64 + ds * 32 + hi8);
        }

    v4f S[4][4];
    #pragma unroll
    for (int qt = 0; qt < 4; qt++)
        #pragma unroll
        for (int kt = 0; kt < 4; kt++) {
            v4f a = (v4f){0.f, 0.f, 0.f, 0.f};
            a = __builtin_amdgcn_mfma_f32_16x16x32_bf16(Qf[qt][0], Kf[kt][0], a, 0, 0, 0);
            a = __builtin_amdgcn_mfma_f32_16x16x32_bf16(Qf[qt][1], Kf[kt][1], a, 0, 0, 0);
            S[qt][kt] = a;
        }

    #pragma unroll
    for (int qt = 0; qt < 4; qt++)
        #pragma unroll
        for (int r = 0; r < 4; r++) {
            float mx = -1e30f;
            #pragma unroll
            for (int kt = 0; kt < 4; kt++) {
                S[qt][kt][r] *= 0.125f;
                mx = fmaxf(mx, S[qt][kt][r]);
            }
            mx = fmaxf(mx, __shfl_xor(mx, 1));
            mx = fmaxf(mx, __shfl_xor(mx, 2));
            mx = fmaxf(mx, __shfl_xor(mx, 4));
            mx = fmaxf(mx, __shfl_xor(mx, 8));
            float sum = 0.f;
            #pragma unroll
            for (int kt = 0; kt < 4; kt++) {
                float e = __expf(S[qt][kt][r] - mx);
                S[qt][kt][r] = e;
                sum += e;
            }
            sum += __shfl_xor(sum, 1);
            sum += __shfl_xor(sum, 2);
            sum += __shfl_xor(sum, 4);
            sum += __shfl_xor(sum, 8);
            float inv = 1.f / sum;
            #pragma unroll
            for (int kt = 0; kt < 4; kt++)
                Ps[(qt * 16 + hi4 + r) * 72 + kt * 16 + li] = f2b(S[qt][kt][r] * inv);
        }

    v4f O[4][4];
    #pragma unroll
    for (int qt = 0; qt < 4; qt++)
        #pragma unroll
        for (int jt = 0; jt < 4; jt++) O[qt][jt] = (v4f){0.f, 0.f, 0.f, 0.f};
    #pragma unroll
    for (int ks = 0; ks < 2; ks++) {
        v8s Pf[4], Vf[4];
        #pragma unroll
        for (int qt = 0; qt < 4; qt++)
            Pf[qt] = *(v8s*)&Ps[(qt * 16 + li) * 72 + ks * 32 + hi8];
        #pragma unroll
        for (int jt = 0; jt < 4; jt++)
            Vf[jt] = *(v8s*)&Vt[(jt * 16 + li) * 72 + ks * 32 + hi8];
        #pragma unroll
        for (int qt = 0; qt < 4; qt++)
            #pragma unroll
            for (int jt = 0; jt < 4; jt++)
                O[qt][jt] = __builtin_amdgcn_mfma_f32_16x16x32_bf16(Pf[qt], Vf[jt], O[qt][jt], 0, 0, 0);
    }

    #pragma unroll
    for (int qt = 0; qt < 4; qt++)
        #pragma unroll
        for (int jt = 0; jt < 4; jt++)
            #pragma unroll
            for (int r = 0; r < 4; r++)
                Ps[(qt * 16 + hi4 + r) * 72 + jt * 16 + li] = f2b(O[qt][jt][r]);
    US* ob = o + (size_t)(g * 64 + l) * 256;
    #pragma unroll
    for (int jv = 0; jv < 8; jv++)
        *(v8us*)(ob + jv * 8) = *(v8us*)&Ps[l * 72 + jv * 8];
}

// ---------------------------------------------------------------- BN affine (stats fused into GEMM epilogue)
__global__ __launch_bounds__(256) void affine_k(const float* __restrict__ g,
                                                const float* __restrict__ b, int sel) {
    int c = threadIdx.x;
    float mean = g_stats[c] / (float)N_NODES;
    float var  = g_stats[CCH + c] / (float)N_NODES - mean * mean;
    float a = g[c] * rsqrtf(var + 1e-5f);
    float* dst = (sel == 0) ? g_aff1 : (sel == 1) ? g_aff2 : g_aff3;
    dst[c] = a;
    dst[CCH + c] = b[c] - mean * a;
    g_stats[c] = 0.f;
    g_stats[CCH + c] = 0.f;
}

// ---------------------------------------------------------------- pool (applies aff3 analytically) + head
__global__ __launch_bounds__(256) void pool_k(const US* __restrict__ h,
                                              float* __restrict__ pooled) {
    int g = blockIdx.x, c = threadIdx.x;
    float s = 0.f;
    for (int ss = 0; ss < SEQ; ss++) s += b2f(h[((size_t)g * SEQ + ss) * CCH + c]);
    pooled[(size_t)g * CCH + c] = g_aff3[c] * s + 64.f * g_aff3[CCH + c];
}

__global__ __launch_bounds__(128) void head_k(const float* __restrict__ pooled,
                                              const float* __restrict__ w1, const float* __restrict__ b1,
                                              const float* __restrict__ w2, const float* __restrict__ b2,
                                              const float* __restrict__ w3, const float* __restrict__ b3,
                                              float* __restrict__ outp) {
    __shared__ float p[256], t1[128], t2[64];
    int g = blockIdx.x, tid = threadIdx.x;
    p[tid] = pooled[(size_t)g * CCH + tid];
    p[tid + 128] = pooled[(size_t)g * CCH + 128 + tid];
    __syncthreads();
    float s = b1[tid];
    for (int k = 0; k < 256; k++) s += p[k] * w1[k * 128 + tid];
    t1[tid] = fmaxf(s, 0.f);
    __syncthreads();
    if (tid < 64) {
        float s2 = b2[tid];
        for (int k = 0; k < 128; k++) s2 += t1[k] * w2[k * 64 + tid];
        t2[tid] = fmaxf(s2, 0.f);
    }
    __syncthreads();
    if (tid == 0) {
        float s3 = b3[0];
        for (int k = 0; k < 64; k++) s3 += t2[k] * w3[k];
        outp[g] = s3;
    }
}

// ================================================================ launch
extern "C" void kernel_launch(void* const* d_in, const int* in_sizes, int n_in,
                              void* d_out, int out_size, void* d_ws, size_t ws_size,
                              hipStream_t stream) {
    const int*   x         = (const int*)  d_in[0];
    const float* pe        = (const float*)d_in[1];
    const int*   ei        = (const int*)  d_in[2];
    const int*   eattr     = (const int*)  d_in[3];
    const float* node_emb  = (const float*)d_in[5];
    const float* pe_lin_w  = (const float*)d_in[6];
    const float* pe_lin_b  = (const float*)d_in[7];
    const float* pe_norm_g = (const float*)d_in[8];
    const float* pe_norm_b = (const float*)d_in[9];
    const float* edge_emb  = (const float*)d_in[10];
    const float* conv_w1   = (const float*)d_in[11];
    const float* conv_b1   = (const float*)d_in[12];
    const float* conv_w2   = (const float*)d_in[13];
    const float* conv_b2   = (const float*)d_in[14];
    const float* attn_in_w = (const float*)d_in[15];
    const float* attn_in_b = (const float*)d_in[16];
    const float* attn_out_w= (const float*)d_in[17];
    const float* attn_out_b= (const float*)d_in[18];
    const float* bn1_g     = (const float*)d_in[19];
    const float* bn1_b     = (const float*)d_in[20];
    const float* bn2_g     = (const float*)d_in[21];
    const float* bn2_b     = (const float*)d_in[22];
    const float* bn3_g     = (const float*)d_in[23];
    const float* bn3_b     = (const float*)d_in[24];
    const float* mlp_w1    = (const float*)d_in[25];
    const float* mlp_b1    = (const float*)d_in[26];
    const float* mlp_w2    = (const float*)d_in[27];
    const float* mlp_b2    = (const float*)d_in[28];
    const float* head_w1   = (const float*)d_in[29];
    const float* head_b1   = (const float*)d_in[30];
    const float* head_w2   = (const float*)d_in[31];
    const float* head_b2   = (const float*)d_in[32];
    const float* head_w3   = (const float*)d_in[33];
    const float* head_b3   = (const float*)d_in[34];
    (void)in_sizes; (void)n_in; (void)out_size; (void)ws_size;

    // workspace: 4 x 64 MB bf16 [N,256] buffers = 256 MB total (proven safe)
    char* ws = (char*)d_ws;
    US* h = (US*)(ws);
    US* A = (US*)(ws + 67108864ULL);
    US* B = (US*)(ws + 134217728ULL);
    US* C = (US*)(ws + 201326592ULL);
    float* pooled = (float*)(ws + 67108864ULL);   // reuses A (dead after layer loop)

    wt_k<<<960, 256, 0, stream>>>(conv_w1, conv_w2, attn_in_w, attn_out_w, mlp_w1, mlp_w2);
    csr_k<<<N_GRAPHS_, 256, 0, stream>>>(ei, eattr);
    pe_part_k<<<256, 256, 0, stream>>>(pe);
    pe_fin_k<<<1, 64, 0, stream>>>(pe_norm_g, pe_norm_b);
    embed_k<<<N_NODES, 256, 0, stream>>>(x, pe, node_emb, pe_lin_w, pe_lin_b, h);

    for (int l = 0; l < LAYERS; l++) {
        size_t wl = (size_t)l * 655360;

        // ---- local GINEConv (aggr applies prev layer's bn3 affine in place) ----
        aggr_z_k<<<N_GRAPHS_, 256, 0, stream>>>(h, edge_emb, A, l == 0 ? 0 : 1);        // z=A, h normalized
        mlp_fused_k<1, false><<<2048, 256, 0, stream>>>(A, nullptr, wl, conv_b1 + l * 256,
                                                        wl + 65536, 256, conv_b2 + l * 256,
                                                        h, C);                          // y1=C + stats
        affine_k<<<1, 256, 0, stream>>>(bn1_g + l * 256, bn1_b + l * 256, 0);

        // ---- global attention (split form: q|k|v -> A per head, o -> B col blocks) ----
        for (int hh = 0; hh < 4; hh++) {
            gemm_mfma_k<3, false><<<2048, 256, 0, stream>>>(h, wl + 131072, 256,
                                                            hh * 64, 256 + hh * 64, 512 + hh * 64, 0,
                                                            attn_in_b + l * 768, nullptr, A, 0);
            attn_k<<<N_GRAPHS_, 64, 0, stream>>>(A, B + hh * 64);
        }
        gemm_mfma_k<4, true><<<2048, 256, 0, stream>>>(B, wl + 327680, 256, 0, 64, 128, 192,
                                                       attn_out_b + l * 256, h, h, 2);  // y2->h + stats
        affine_k<<<1, 256, 0, stream>>>(bn2_g + l * 256, bn2_b + l * 256, 1);

        // ---- fused combine + FFN (combine computed on the fly from C and h) ----
        mlp_fused_k<2, true><<<2048, 256, 0, stream>>>(C, h, wl + 393216, mlp_b1 + l * 512,
                                                       wl + 524288, 512, mlp_b2 + l * 256,
                                                       nullptr, h);                     // y3->h + stats
        affine_k<<<1, 256, 0, stream>>>(bn3_g + l * 256, bn3_b + l * 256, 2);
        // (bn3 affine applied lazily: next layer's aggr, or pool for the last layer)
    }

    pool_k<<<N_GRAPHS_, 256, 0, stream>>>(h, pooled);
    head_k<<<N_GRAPHS_, 128, 0, stream>>>(pooled, head_w1, head_b1, head_w2, head_b2,
                                          head_w3, head_b3, (float*)d_out);
}

// Round 16
// 5047.513 us; speedup vs baseline: 1.0371x; 1.0371x over previous
//
#include <hip/hip_runtime.h>

#define N_NODES 131072
#define N_EDGES 524288
#define CCH 256
#define N_GRAPHS_ 2048
#define SEQ 64
#define LAYERS 6

typedef unsigned short US;
typedef __attribute__((ext_vector_type(8))) short v8s;           // MFMA bf16 frag
typedef __attribute__((ext_vector_type(8))) unsigned short v8us; // 16B ushort vector
typedef __attribute__((ext_vector_type(4))) float v4f;           // MFMA f32 acc

__device__ __forceinline__ float b2f(US u) { return __uint_as_float(((unsigned)u) << 16); }
__device__ __forceinline__ US f2b(float f) {
    unsigned u = __float_as_uint(f);
    return (US)((u + 0x7fff + ((u >> 16) & 1)) >> 16);   // RNE
}
__device__ __forceinline__ void gload16(const US* g, US* l) {
    __builtin_amdgcn_global_load_lds(
        (const __attribute__((address_space(1))) unsigned int*)g,
        (__attribute__((address_space(3))) unsigned int*)l, 16, 0, 0);
}

// cross-kernel state — referenced ONLY inside device code (never from host!)
__device__ float g_stats[512];
__device__ float g_aff1[512];
__device__ float g_aff2[512];
__device__ float g_aff3[512];
__device__ float g_pe[40];
__device__ float g_peaff[40];
__device__ US    g_wt[6 * 655360];          // per-layer transposed bf16 weights
__device__ int   g_csr[N_EDGES];            // per-graph dst-sorted edges: srcLocal | attr<<6
__device__ int   g_off[N_GRAPHS_ * 65];     // per-graph CSR offsets

// ---------------------------------------------------------------- weight transpose f32[K][C] -> bf16[C][K]
__global__ __launch_bounds__(256) void wt_k(const float* __restrict__ cw1, const float* __restrict__ cw2,
                                            const float* __restrict__ aiw, const float* __restrict__ aow,
                                            const float* __restrict__ mw1, const float* __restrict__ mw2) {
    __shared__ float t[64][65];
    int b = blockIdx.x;
    int l = b / 160, r = b % 160;
    const float* src; int ldw, ldk, ctiles; size_t doff;
    if (r < 16)      { src = cw1 + (size_t)l * 65536;  ldw = 256; ldk = 256; ctiles = 4;  doff = 0;      }
    else if (r < 32) { src = cw2 + (size_t)l * 65536;  ldw = 256; ldk = 256; ctiles = 4;  doff = 65536;  r -= 16; }
    else if (r < 80) { src = aiw + (size_t)l * 196608; ldw = 768; ldk = 256; ctiles = 12; doff = 131072; r -= 32; }
    else if (r < 96) { src = aow + (size_t)l * 65536;  ldw = 256; ldk = 256; ctiles = 4;  doff = 327680; r -= 80; }
    else if (r < 128){ src = mw1 + (size_t)l * 131072; ldw = 512; ldk = 256; ctiles = 8;  doff = 393216; r -= 96; }
    else             { src = mw2 + (size_t)l * 131072; ldw = 256; ldk = 512; ctiles = 4;  doff = 524288; r -= 128; }
    int kt = r / ctiles, ct = r % ctiles;
    int k0 = kt * 64, c0 = ct * 64;
    US* dst = g_wt + (size_t)l * 655360 + doff;
    int tid = threadIdx.x;
    int rr = tid >> 4, c4 = (tid & 15) * 4;
    #pragma unroll
    for (int j = 0; j < 4; j++) {
        float4 v = *(const float4*)(src + (size_t)(k0 + rr + j * 16) * ldw + c0 + c4);
        t[rr + j * 16][c4 + 0] = v.x; t[rr + j * 16][c4 + 1] = v.y;
        t[rr + j * 16][c4 + 2] = v.z; t[rr + j * 16][c4 + 3] = v.w;
    }
    __syncthreads();
    #pragma unroll
    for (int j = 0; j < 4; j++) {
        int crow = rr + j * 16;
        ushort4 o;
        o.x = f2b(t[c4 + 0][crow]); o.y = f2b(t[c4 + 1][crow]);
        o.z = f2b(t[c4 + 2][crow]); o.w = f2b(t[c4 + 3][crow]);
        *(ushort4*)(dst + (size_t)(c0 + crow) * ldk + k0 + c4) = o;
    }
}

// ---------------------------------------------------------------- CSR build (once per launch)
__global__ __launch_bounds__(256) void csr_k(const int* __restrict__ ei,
                                             const int* __restrict__ attr) {
    __shared__ int deg[64], off[65];
    int g = blockIdx.x, tid = threadIdx.x;
    if (tid < 64) deg[tid] = 0;
    __syncthreads();
    int e = g * 256 + tid;
    int d = ei[N_EDGES + e] - g * 64;
    int slot = atomicAdd(&deg[d], 1);
    __syncthreads();
    if (tid == 0) {
        off[0] = 0;
        for (int i = 0; i < 64; i++) off[i + 1] = off[i] + deg[i];
    }
    __syncthreads();
    g_csr[g * 256 + off[d] + slot] = (ei[e] - g * 64) | (attr[e] << 6);
    if (tid < 65) g_off[g * 65 + tid] = off[tid];
}

// ---------------------------------------------------------------- pe stats (2-stage)
__global__ __launch_bounds__(256) void pe_part_k(const float* __restrict__ pe) {
    __shared__ float red[240], red2[240];
    int b = blockIdx.x, tid = threadIdx.x;
    float s = 0.f, s2 = 0.f;
    if (tid < 240) {
        int ch = tid % 20, sub = tid / 20;
        size_t r0 = (size_t)b * 512;
        for (int r = sub; r < 512; r += 12) {
            float v = pe[(r0 + r) * 20 + ch];
            s += v; s2 += v * v;
        }
        red[tid] = s; red2[tid] = s2;
    }
    __syncthreads();
    if (tid < 20) {
        float ts = 0.f, ts2 = 0.f;
        #pragma unroll
        for (int sub = 0; sub < 12; sub++) { ts += red[sub * 20 + tid]; ts2 += red2[sub * 20 + tid]; }
        atomicAdd(&g_pe[tid], ts);
        atomicAdd(&g_pe[20 + tid], ts2);
    }
}

__global__ __launch_bounds__(64) void pe_fin_k(const float* __restrict__ g,
                                               const float* __restrict__ b) {
    int t = threadIdx.x;
    if (t < 20) {
        float mean = g_pe[t] / (float)N_NODES;
        float var  = g_pe[20 + t] / (float)N_NODES - mean * mean;
        float a = g[t] * rsqrtf(var + 1e-5f);
        g_peaff[t] = a;
        g_peaff[20 + t] = b[t] - mean * a;
        g_pe[t] = 0.f;          // re-zero for deterministic replay
        g_pe[20 + t] = 0.f;
    }
}

// ---------------------------------------------------------------- embed
__global__ __launch_bounds__(256) void embed_k(const int* __restrict__ x,
                                               const float* __restrict__ pe,
                                               const float* __restrict__ node_emb,
                                               const float* __restrict__ plw,
                                               const float* __restrict__ plb,
                                               US* __restrict__ h) {
    int n = blockIdx.x;
    int tid = threadIdx.x;
    int xi = x[n];
    float v;
    if (tid < 192) {
        v = node_emb[xi * 192 + tid];
    } else {
        int j = tid - 192;
        float s = plb[j];
        #pragma unroll
        for (int k = 0; k < 20; k++) {
            float p = pe[(size_t)n * 20 + k] * g_peaff[k] + g_peaff[20 + k];
            s += p * plw[k * 64 + j];
        }
        v = s;
    }
    h[(size_t)n * CCH + tid] = f2b(v);
}

// ---------------------------------------------------------------- edge aggregation: CSR, no atomics
// useAff: first apply h' = aff3(h) in place (block owns its graph's rows; gathers use LDS tile)
__global__ __launch_bounds__(256) void aggr_z_k(US* __restrict__ h,
                                                const float* __restrict__ eemb,
                                                US* __restrict__ z, int useAff) {
    __shared__ US ht[64 * 264];
    __shared__ float em[4 * 260];
    __shared__ int off[65], ce[256];
    int g = blockIdx.x, tid = threadIdx.x;
    for (int v = tid; v < 2048; v += 256) {
        int row = v >> 5, seg = (v & 31) * 8;
        v8us hv = *(const v8us*)(h + (size_t)(g * 64 + row) * 256 + seg);
        if (useAff) {
            v8us o;
            #pragma unroll
            for (int j = 0; j < 8; j++)
                o[j] = f2b(b2f(hv[j]) * g_aff3[seg + j] + g_aff3[CCH + seg + j]);
            hv = o;
            *(v8us*)(h + (size_t)(g * 64 + row) * 256 + seg) = hv;   // normalized h in place
        }
        *(v8us*)&ht[row * 264 + seg] = hv;
    }
    for (int i = tid; i < 1024; i += 256)
        em[(i >> 8) * 260 + (i & 255)] = eemb[(i >> 8) * 256 + (i & 255)];
    ce[tid] = g_csr[g * 256 + tid];
    if (tid < 65) off[tid] = g_off[g * 65 + tid];
    __syncthreads();

    int dst = tid >> 2, cq = (tid & 3) * 4;
    float acc[64];
    #pragma unroll
    for (int i = 0; i < 64; i++) acc[i] = 0.f;
    int e1 = off[dst + 1];
    for (int e = off[dst]; e < e1; e++) {
        int val = ce[e];
        int src = val & 63, a = (val >> 6) & 3;
        #pragma unroll
        for (int i = 0; i < 16; i++) {
            int c = cq + i * 16;
            ushort4 hv = *(ushort4*)&ht[src * 264 + c];
            float4 ev = *(float4*)&em[a * 260 + c];
            acc[i * 4 + 0] += fmaxf(b2f(hv.x) + ev.x, 0.f);
            acc[i * 4 + 1] += fmaxf(b2f(hv.y) + ev.y, 0.f);
            acc[i * 4 + 2] += fmaxf(b2f(hv.z) + ev.z, 0.f);
            acc[i * 4 + 3] += fmaxf(b2f(hv.w) + ev.w, 0.f);
        }
    }
    US* zp = z + (size_t)(g * 64 + dst) * 256;
    #pragma unroll
    for (int i = 0; i < 16; i++) {
        int c = cq + i * 16;
        ushort4 hv = *(ushort4*)&ht[dst * 264 + c];
        ushort4 o;
        o.x = f2b(b2f(hv.x) + acc[i * 4 + 0]);
        o.y = f2b(b2f(hv.y) + acc[i * 4 + 1]);
        o.z = f2b(b2f(hv.z) + acc[i * 4 + 2]);
        o.w = f2b(b2f(hv.w) + acc[i * 4 + 3]);
        *(ushort4*)(zp + c) = o;
    }
}

// ---------------------------------------------------------------- MFMA bf16 GEMM  (BM=64, EXACT round-10 version)
template<int NG, bool STATS>
__global__ __launch_bounds__(256, 4) void gemm_mfma_k(const US* __restrict__ A,
                                                      size_t woff, int ldk,
                                                      int w0, int w1, int w2, int w3,
                                                      const float* __restrict__ bias,
                                                      const US* __restrict__ res,
                                                      US* __restrict__ Y, int mode) {
    const US* __restrict__ Wt = g_wt + woff;
    __shared__ __align__(16) char smem[8192 + 2 * NG * 4096];
    US* As0 = (US*)smem;
    US* As1 = As0 + 2048;
    US* Bs0 = (US*)(smem + 8192);
    US* Bs1 = Bs0 + NG * 2048;
    float* Es = (float*)smem;
    const int NW = NG * 64 + 4;

    int tid = threadIdx.x;
    int bid = blockIdx.x;
    int swz = (bid & 7) * ((int)gridDim.x >> 3) + (bid >> 3);
    size_t row0 = (size_t)swz * 64;
    int w = tid >> 6, l = tid & 63;
    int li = l & 15, hi = l >> 4;
    int sl = hi ^ ((li >> 1) & 3);
    int sr = l >> 2, ss = l & 3;

    int a_off = (w * 16 + li) * 32 + sl * 8;

    v4f acc[NG * 4];
    #pragma unroll
    for (int t = 0; t < NG * 4; t++) acc[t] = (v4f){0.f, 0.f, 0.f, 0.f};

    int ar = w * 16 + sr;
    int akg = (ss ^ ((ar >> 1) & 3)) * 8;
    const US* asrc = A + (row0 + ar) * 256 + akg;

    auto stage = [&](int kc, US* Asb, US* Bsb) {
        int k0 = kc * 32;
        gload16(asrc + k0, Asb + w * 512);
        #pragma unroll
        for (int j = 0; j < NG; j++) {
            int cu = (j * 4 + w) * 16 + sr;
            int grp = cu >> 6;
            int wb = (grp == 0) ? w0 : (grp == 1) ? w1 : (grp == 2) ? w2 : w3;
            int kg = (ss ^ ((cu >> 1) & 3)) * 8;
            gload16(Wt + (size_t)(wb + (cu & 63)) * ldk + k0 + kg,
                    Bsb + (j * 4 + w) * 512);
        }
    };

    stage(0, As0, Bs0);
    __syncthreads();
    for (int kc = 0; kc < 8; kc++) {
        US* Asc = (kc & 1) ? As1 : As0;
        US* Bsc = (kc & 1) ? Bs1 : Bs0;
        if (kc < 7) stage(kc + 1, (kc & 1) ? As0 : As1, (kc & 1) ? Bs0 : Bs1);
        v8s a0 = *(v8s*)(Asc + a_off);
        #pragma unroll
        for (int t = 0; t < NG * 4; t++) {
            v8s bf = *(v8s*)(Bsc + (t * 16 + li) * 32 + sl * 8);
            acc[t] = __builtin_amdgcn_mfma_f32_16x16x32_bf16(a0, bf, acc[t], 0, 0, 0);
        }
        __syncthreads();
    }

    int er_f = tid >> 3;
    int lcb = (tid & 7) * 8;
    float csum = 0.f, csum2 = 0.f;
    #pragma unroll
    for (int p = 0; p < 2; p++) {
        if ((w >> 1) == p) {
            int er0 = (w & 1) * 16 + hi * 4;
            #pragma unroll
            for (int t = 0; t < NG * 4; t++) {
                int grp = t >> 2;
                int wb = (grp == 0) ? w0 : (grp == 1) ? w1 : (grp == 2) ? w2 : w3;
                float bv = bias ? bias[wb + (t & 3) * 16 + li] : 0.f;
                #pragma unroll
                for (int r = 0; r < 4; r++) {
                    float v = acc[t][r] + bv;
                    if (mode == 1) v = fmaxf(v, 0.f);
                    Es[(er0 + r) * NW + t * 16 + li] = v;
                }
            }
        }
        __syncthreads();
        size_t gr = row0 + p * 32 + er_f;
        #pragma unroll
        for (int s = 0; s < NG; s++) {
            int c = s * 64 + lcb;
            float vs[8];
            #pragma unroll
            for (int j = 0; j < 8; j++) vs[j] = Es[er_f * NW + c + j];
            if (mode == 2) {
                v8us rv = *(const v8us*)(res + gr * 256 + c);
                #pragma unroll
                for (int j = 0; j < 8; j++) vs[j] += b2f(rv[j]);
            }
            v8us yv;
            #pragma unroll
            for (int j = 0; j < 8; j++) yv[j] = f2b(vs[j]);
            *(v8us*)(Y + gr * 256 + c) = yv;
            if constexpr (STATS) {
                #pragma unroll
                for (int j = 0; j < 8; j++) Es[er_f * NW + c + j] = vs[j];
            }
        }
        if constexpr (STATS) {
            __syncthreads();
            if (tid < NG * 64) {
                float s1 = 0.f, s2 = 0.f;
                #pragma unroll 8
                for (int r2 = 0; r2 < 32; r2++) {
                    float vv = Es[r2 * NW + tid];
                    s1 += vv; s2 += vv * vv;
                }
                csum += s1; csum2 += s2;
            }
        }
        __syncthreads();
    }
    if constexpr (STATS) {
        if (tid < NG * 64) {
            atomicAdd(&g_stats[tid], csum);
            atomicAdd(&g_stats[CCH + tid], csum2);
        }
    }
}

// ---------------------------------------------------------------- FUSED chained GEMM: Y = relu(A@W1+b1)@W2 + b2 + res
// EXACT round-14 version (gload_lds staging, no COMB). NH 256-wide t-chunks.
template<int NH>
__global__ __launch_bounds__(256, 2) void mlp_fused_k(const US* __restrict__ A,
                                                      size_t woff1, const float* __restrict__ bias1,
                                                      size_t woff2, int ldk2,
                                                      const float* __restrict__ bias2,
                                                      const US* __restrict__ res,
                                                      US* __restrict__ Y) {
    const US* __restrict__ W1t = g_wt + woff1;
    const US* __restrict__ W2t = g_wt + woff2;
    __shared__ __align__(16) char smem[73728];
    US* As0 = (US*)smem;
    US* As1 = (US*)(smem + 4096);
    US* Bs0 = (US*)(smem + 8192);
    US* Bs1 = (US*)(smem + 24576);
    float* Es = (float*)smem;
    US* Ts = (US*)(smem + 40960);

    int tid = threadIdx.x;
    int bid = blockIdx.x;
    int swz = (bid & 7) * ((int)gridDim.x >> 3) + (bid >> 3);
    size_t row0 = (size_t)swz * 64;
    int w = tid >> 6, l = tid & 63;
    int li = l & 15, hi = l >> 4;
    int sl = hi ^ ((li >> 1) & 3);
    int sr = l >> 2, ss = l & 3;

    int a_off = (w * 16 + li) * 32 + sl * 8;

    v4f accY[16];
    #pragma unroll
    for (int t = 0; t < 16; t++) accY[t] = (v4f){0.f, 0.f, 0.f, 0.f};

    int ar = w * 16 + sr;
    int akg = (ss ^ ((ar >> 1) & 3)) * 8;
    const US* asrc = A + (row0 + ar) * 256 + akg;

    #pragma unroll
    for (int q = 0; q < NH; q++) {
        v4f accT[16];
        #pragma unroll
        for (int t = 0; t < 16; t++) accT[t] = (v4f){0.f, 0.f, 0.f, 0.f};

        auto stageA = [&](int kc, US* Asb, US* Bsb) {
            int k0 = kc * 32;
            gload16(asrc + k0, Asb + w * 512);
            #pragma unroll
            for (int j = 0; j < 4; j++) {
                int cu = (j * 4 + w) * 16 + sr;
                int kg = (ss ^ ((cu >> 1) & 3)) * 8;
                gload16(W1t + (size_t)(q * 256 + cu) * 256 + k0 + kg,
                        Bsb + (j * 4 + w) * 512);
            }
        };
        stageA(0, As0, Bs0);
        __syncthreads();
        for (int kc = 0; kc < 8; kc++) {
            US* Asc = (kc & 1) ? As1 : As0;
            US* Bsc = (kc & 1) ? Bs1 : Bs0;
            if (kc < 7) stageA(kc + 1, (kc & 1) ? As0 : As1, (kc & 1) ? Bs0 : Bs1);
            v8s a0 = *(v8s*)(Asc + a_off);
            #pragma unroll
            for (int t = 0; t < 16; t++) {
                v8s bf = *(v8s*)(Bsc + (t * 16 + li) * 32 + sl * 8);
                accT[t] = __builtin_amdgcn_mfma_f32_16x16x32_bf16(a0, bf, accT[t], 0, 0, 0);
            }
            __syncthreads();
        }
        // ---- t -> Ts via Es transpose (bias + relu + bf16 round) ----
        #pragma unroll
        for (int p = 0; p < 2; p++) {
            if ((w >> 1) == p) {
                int er0 = (w & 1) * 16 + hi * 4;
                #pragma unroll
                for (int t = 0; t < 16; t++) {
                    float bv = bias1[q * 256 + t * 16 + li];
                    #pragma unroll
                    for (int r = 0; r < 4; r++)
                        Es[(er0 + r) * 260 + t * 16 + li] = fmaxf(accT[t][r] + bv, 0.f);
                }
            }
            __syncthreads();
            {
                int er = tid >> 3, lcb = (tid & 7) * 8;
                int rowL = p * 32 + er;
                int rsw = (rowL >> 1) & 3;
                #pragma unroll
                for (int s = 0; s < 4; s++) {
                    int col = s * 64 + lcb;
                    v8us tv;
                    #pragma unroll
                    for (int j = 0; j < 8; j++) tv[j] = f2b(Es[er * 260 + col + j]);
                    int chunk = col >> 5, slot = ((col >> 3) & 3) ^ rsw;
                    *(v8us*)&Ts[chunk * 2048 + rowL * 32 + slot * 8] = tv;
                }
            }
            __syncthreads();
        }
        // ---- phase B: accY += t @ W2[q*256 + k][:] ----
        auto stageB = [&](int kc, US* Bsb) {
            int k0 = q * 256 + kc * 32;
            #pragma unroll
            for (int j = 0; j < 4; j++) {
                int cu = (j * 4 + w) * 16 + sr;
                int kg = (ss ^ ((cu >> 1) & 3)) * 8;
                gload16(W2t + (size_t)cu * ldk2 + k0 + kg, Bsb + (j * 4 + w) * 512);
            }
        };
        stageB(0, Bs0);
        __syncthreads();
        for (int kc = 0; kc < 8; kc++) {
            US* Bsc = (kc & 1) ? Bs1 : Bs0;
            if (kc < 7) stageB(kc + 1, (kc & 1) ? Bs0 : Bs1);
            v8s a0 = *(v8s*)(Ts + kc * 2048 + a_off);
            #pragma unroll
            for (int t = 0; t < 16; t++) {
                v8s bf = *(v8s*)(Bsc + (t * 16 + li) * 32 + sl * 8);
                accY[t] = __builtin_amdgcn_mfma_f32_16x16x32_bf16(a0, bf, accY[t], 0, 0, 0);
            }
            __syncthreads();
        }
    }

    // ---- final epilogue: bias2 + res + stats -> Y ----
    int er_f = tid >> 3;
    int lcb = (tid & 7) * 8;
    float csum = 0.f, csum2 = 0.f;
    #pragma unroll
    for (int p = 0; p < 2; p++) {
        if ((w >> 1) == p) {
            int er0 = (w & 1) * 16 + hi * 4;
            #pragma unroll
            for (int t = 0; t < 16; t++) {
                float bv = bias2[t * 16 + li];
                #pragma unroll
                for (int r = 0; r < 4; r++)
                    Es[(er0 + r) * 260 + t * 16 + li] = accY[t][r] + bv;
            }
        }
        __syncthreads();
        size_t gr = row0 + p * 32 + er_f;
        #pragma unroll
        for (int s = 0; s < 4; s++) {
            int c = s * 64 + lcb;
            float vs[8];
            #pragma unroll
            for (int j = 0; j < 8; j++) vs[j] = Es[er_f * 260 + c + j];
            v8us rv = *(const v8us*)(res + gr * 256 + c);
            #pragma unroll
            for (int j = 0; j < 8; j++) vs[j] += b2f(rv[j]);
            v8us yv;
            #pragma unroll
            for (int j = 0; j < 8; j++) yv[j] = f2b(vs[j]);
            *(v8us*)(Y + gr * 256 + c) = yv;
            #pragma unroll
            for (int j = 0; j < 8; j++) Es[er_f * 260 + c + j] = vs[j];
        }
        __syncthreads();
        {
            float s1 = 0.f, s2 = 0.f;
            #pragma unroll 8
            for (int r2 = 0; r2 < 32; r2++) {
                float vv = Es[r2 * 260 + tid];
                s1 += vv; s2 += vv * vv;
            }
            csum += s1; csum2 += s2;
        }
        __syncthreads();
    }
    atomicAdd(&g_stats[tid], csum);
    atomicAdd(&g_stats[CCH + tid], csum2);
}

// ---------------------------------------------------------------- MFMA attention: 1 wave = (graph, head)  [R10]
__global__ __launch_bounds__(64) void attn_k(const US* __restrict__ qkv,
                                             US* __restrict__ o) {
    __shared__ __align__(16) US Ps[64 * 72];
    __shared__ __align__(16) US Vt[64 * 72];
    int g = blockIdx.x, l = threadIdx.x;
    int li = l & 15, hi8 = (l >> 4) * 8, hi4 = (l >> 4) * 4;
    const US* base = qkv + (size_t)g * 64 * 256;

    {
        v8us vv[8];
        #pragma unroll
        for (int jv = 0; jv < 8; jv++)
            vv[jv] = *(const v8us*)(base + l * 256 + 128 + jv * 8);
        #pragma unroll
        for (int jv = 0; jv < 8; jv++)
            #pragma unroll
            for (int e = 0; e < 8; e++)
                Vt[(jv * 8 + e) * 72 + l] = vv[jv][e];
    }

    v8s Qf[4][2], Kf[4][2];
    #pragma unroll
    for (int t = 0; t < 4; t++)
        #pragma unroll
        for (int ds = 0; ds < 2; ds++) {
            Qf[t][ds] = *(const v8s*)(base + (t * 16 + li) * 256 + ds * 32 + hi8);
            Kf[t][ds] = *(const v8s*)(base + (t * 16 + li) * 256 + 64 + ds * 32 + hi8);
        }

    v4f S[4][4];
    #pragma unroll
    for (int qt = 0; qt < 4; qt++)
        #pragma unroll
        for (int kt = 0; kt < 4; kt++) {
            v4f a = (v4f){0.f, 0.f, 0.f, 0.f};
            a = __builtin_amdgcn_mfma_f32_16x16x32_bf16(Qf[qt][0], Kf[kt][0], a, 0, 0, 0);
            a = __builtin_amdgcn_mfma_f32_16x16x32_bf16(Qf[qt][1], Kf[kt][1], a, 0, 0, 0);
            S[qt][kt] = a;
        }

    #pragma unroll
    for (int qt = 0; qt < 4; qt++)
        #pragma unroll
        for (int r = 0; r < 4; r++) {
            float mx = -1e30f;
            #pragma unroll
            for (int kt = 0; kt < 4; kt++) {
                S[qt][kt][r] *= 0.125f;
                mx = fmaxf(mx, S[qt][kt][r]);
            }
            mx = fmaxf(mx, __shfl_xor(mx, 1));
            mx = fmaxf(mx, __shfl_xor(mx, 2));
            mx = fmaxf(mx, __shfl_xor(mx, 4));
            mx = fmaxf(mx, __shfl_xor(mx, 8));
            float sum = 0.f;
            #pragma unroll
            for (int kt = 0; kt < 4; kt++) {
                float e = __expf(S[qt][kt][r] - mx);
                S[qt][kt][r] = e;
                sum += e;
            }
            sum += __shfl_xor(sum, 1);
            sum += __shfl_xor(sum, 2);
            sum += __shfl_xor(sum, 4);
            sum += __shfl_xor(sum, 8);
            float inv = 1.f / sum;
            #pragma unroll
            for (int kt = 0; kt < 4; kt++)
                Ps[(qt * 16 + hi4 + r) * 72 + kt * 16 + li] = f2b(S[qt][kt][r] * inv);
        }

    v4f O[4][4];
    #pragma unroll
    for (int qt = 0; qt < 4; qt++)
        #pragma unroll
        for (int jt = 0; jt < 4; jt++) O[qt][jt] = (v4f){0.f, 0.f, 0.f, 0.f};
    #pragma unroll
    for (int ks = 0; ks < 2; ks++) {
        v8s Pf[4], Vf[4];
        #pragma unroll
        for (int qt = 0; qt < 4; qt++)
            Pf[qt] = *(v8s*)&Ps[(qt * 16 + li) * 72 + ks * 32 + hi8];
        #pragma unroll
        for (int jt = 0; jt < 4; jt++)
            Vf[jt] = *(v8s*)&Vt[(jt * 16 + li) * 72 + ks * 32 + hi8];
        #pragma unroll
        for (int qt = 0; qt < 4; qt++)
            #pragma unroll
            for (int jt = 0; jt < 4; jt++)
                O[qt][jt] = __builtin_amdgcn_mfma_f32_16x16x32_bf16(Pf[qt], Vf[jt], O[qt][jt], 0, 0, 0);
    }

    #pragma unroll
    for (int qt = 0; qt < 4; qt++)
        #pragma unroll
        for (int jt = 0; jt < 4; jt++)
            #pragma unroll
            for (int r = 0; r < 4; r++)
                Ps[(qt * 16 + hi4 + r) * 72 + jt * 16 + li] = f2b(O[qt][jt][r]);
    US* ob = o + (size_t)(g * 64 + l) * 256;
    #pragma unroll
    for (int jv = 0; jv < 8; jv++)
        *(v8us*)(ob + jv * 8) = *(v8us*)&Ps[l * 72 + jv * 8];
}

// ---------------------------------------------------------------- BN affine (stats fused into GEMM epilogue)
__global__ __launch_bounds__(256) void affine_k(const float* __restrict__ g,
                                                const float* __restrict__ b, int sel) {
    int c = threadIdx.x;
    float mean = g_stats[c] / (float)N_NODES;
    float var  = g_stats[CCH + c] / (float)N_NODES - mean * mean;
    float a = g[c] * rsqrtf(var + 1e-5f);
    float* dst = (sel == 0) ? g_aff1 : (sel == 1) ? g_aff2 : g_aff3;
    dst[c] = a;
    dst[CCH + c] = b[c] - mean * a;
    g_stats[c] = 0.f;
    g_stats[CCH + c] = 0.f;
}

// ---------------------------------------------------------------- combine (v8us vectorized)
__global__ __launch_bounds__(256) void combine_k(const US* __restrict__ y1,
                                                 const US* __restrict__ y2,
                                                 US* __restrict__ out) {
    size_t idx = (size_t)blockIdx.x * 256 + threadIdx.x;
    size_t stride = (size_t)gridDim.x * 256;
    for (; idx < (size_t)N_NODES * CCH / 8; idx += stride) {
        size_t i = idx * 8;
        int c = (int)(i & 255);
        v8us a = *(const v8us*)(y1 + i);
        v8us b = *(const v8us*)(y2 + i);
        v8us o;
        #pragma unroll
        for (int j = 0; j < 8; j++) {
            float v = b2f(a[j]) * g_aff1[c + j] + g_aff1[CCH + c + j] +
                      b2f(b[j]) * g_aff2[c + j] + g_aff2[CCH + c + j];
            o[j] = f2b(v);
        }
        *(v8us*)(out + i) = o;
    }
}

// ---------------------------------------------------------------- pool (applies aff3 analytically) + head
__global__ __launch_bounds__(256) void pool_k(const US* __restrict__ h,
                                              float* __restrict__ pooled) {
    int g = blockIdx.x, c = threadIdx.x;
    float s = 0.f;
    for (int ss = 0; ss < SEQ; ss++) s += b2f(h[((size_t)g * SEQ + ss) * CCH + c]);
    pooled[(size_t)g * CCH + c] = g_aff3[c] * s + 64.f * g_aff3[CCH + c];
}

__global__ __launch_bounds__(128) void head_k(const float* __restrict__ pooled,
                                              const float* __restrict__ w1, const float* __restrict__ b1,
                                              const float* __restrict__ w2, const float* __restrict__ b2,
                                              const float* __restrict__ w3, const float* __restrict__ b3,
                                              float* __restrict__ outp) {
    __shared__ float p[256], t1[128], t2[64];
    int g = blockIdx.x, tid = threadIdx.x;
    p[tid] = pooled[(size_t)g * CCH + tid];
    p[tid + 128] = pooled[(size_t)g * CCH + 128 + tid];
    __syncthreads();
    float s = b1[tid];
    for (int k = 0; k < 256; k++) s += p[k] * w1[k * 128 + tid];
    t1[tid] = fmaxf(s, 0.f);
    __syncthreads();
    if (tid < 64) {
        float s2 = b2[tid];
        for (int k = 0; k < 128; k++) s2 += t1[k] * w2[k * 64 + tid];
        t2[tid] = fmaxf(s2, 0.f);
    }
    __syncthreads();
    if (tid == 0) {
        float s3 = b3[0];
        for (int k = 0; k < 64; k++) s3 += t2[k] * w3[k];
        outp[g] = s3;
    }
}

// ================================================================ launch
extern "C" void kernel_launch(void* const* d_in, const int* in_sizes, int n_in,
                              void* d_out, int out_size, void* d_ws, size_t ws_size,
                              hipStream_t stream) {
    const int*   x         = (const int*)  d_in[0];
    const float* pe        = (const float*)d_in[1];
    const int*   ei        = (const int*)  d_in[2];
    const int*   eattr     = (const int*)  d_in[3];
    const float* node_emb  = (const float*)d_in[5];
    const float* pe_lin_w  = (const float*)d_in[6];
    const float* pe_lin_b  = (const float*)d_in[7];
    const float* pe_norm_g = (const float*)d_in[8];
    const float* pe_norm_b = (const float*)d_in[9];
    const float* edge_emb  = (const float*)d_in[10];
    const float* conv_w1   = (const float*)d_in[11];
    const float* conv_b1   = (const float*)d_in[12];
    const float* conv_w2   = (const float*)d_in[13];
    const float* conv_b2   = (const float*)d_in[14];
    const float* attn_in_w = (const float*)d_in[15];
    const float* attn_in_b = (const float*)d_in[16];
    const float* attn_out_w= (const float*)d_in[17];
    const float* attn_out_b= (const float*)d_in[18];
    const float* bn1_g     = (const float*)d_in[19];
    const float* bn1_b     = (const float*)d_in[20];
    const float* bn2_g     = (const float*)d_in[21];
    const float* bn2_b     = (const float*)d_in[22];
    const float* bn3_g     = (const float*)d_in[23];
    const float* bn3_b     = (const float*)d_in[24];
    const float* mlp_w1    = (const float*)d_in[25];
    const float* mlp_b1    = (const float*)d_in[26];
    const float* mlp_w2    = (const float*)d_in[27];
    const float* mlp_b2    = (const float*)d_in[28];
    const float* head_w1   = (const float*)d_in[29];
    const float* head_b1   = (const float*)d_in[30];
    const float* head_w2   = (const float*)d_in[31];
    const float* head_b2   = (const float*)d_in[32];
    const float* head_w3   = (const float*)d_in[33];
    const float* head_b3   = (const float*)d_in[34];
    (void)in_sizes; (void)n_in; (void)out_size; (void)ws_size;

    // workspace: 4 x 64 MB bf16 [N,256] buffers = 256 MB total (proven safe)
    char* ws = (char*)d_ws;
    US* h = (US*)(ws);
    US* A = (US*)(ws + 67108864ULL);
    US* B = (US*)(ws + 134217728ULL);
    US* C = (US*)(ws + 201326592ULL);
    float* pooled = (float*)(ws + 67108864ULL);   // reuses A (dead after layer loop)

    wt_k<<<960, 256, 0, stream>>>(conv_w1, conv_w2, attn_in_w, attn_out_w, mlp_w1, mlp_w2);
    csr_k<<<N_GRAPHS_, 256, 0, stream>>>(ei, eattr);
    pe_part_k<<<256, 256, 0, stream>>>(pe);
    pe_fin_k<<<1, 64, 0, stream>>>(pe_norm_g, pe_norm_b);
    embed_k<<<N_NODES, 256, 0, stream>>>(x, pe, node_emb, pe_lin_w, pe_lin_b, h);

    for (int l = 0; l < LAYERS; l++) {
        size_t wl = (size_t)l * 655360;

        // ---- local GINEConv (aggr applies prev layer's bn3 affine in place) ----
        aggr_z_k<<<N_GRAPHS_, 256, 0, stream>>>(h, edge_emb, A, l == 0 ? 0 : 1);        // z=A, h normalized
        mlp_fused_k<1><<<2048, 256, 0, stream>>>(A, wl, conv_b1 + l * 256,
                                                 wl + 65536, 256, conv_b2 + l * 256,
                                                 h, C);                                 // y1=C + stats
        affine_k<<<1, 256, 0, stream>>>(bn1_g + l * 256, bn1_b + l * 256, 0);

        // ---- global attention (split form: q|k|v -> A per head, o -> B col blocks) ----
        for (int hh = 0; hh < 4; hh++) {
            gemm_mfma_k<3, false><<<2048, 256, 0, stream>>>(h, wl + 131072, 256,
                                                            hh * 64, 256 + hh * 64, 512 + hh * 64, 0,
                                                            attn_in_b + l * 768, nullptr, A, 0);
            attn_k<<<N_GRAPHS_, 64, 0, stream>>>(A, B + hh * 64);
        }
        gemm_mfma_k<4, true><<<2048, 256, 0, stream>>>(B, wl + 327680, 256, 0, 64, 128, 192,
                                                       attn_out_b + l * 256, h, h, 2);  // y2->h + stats
        affine_k<<<1, 256, 0, stream>>>(bn2_g + l * 256, bn2_b + l * 256, 1);

        // ---- combine + fused FFN ----
        combine_k<<<2048, 256, 0, stream>>>(C, h, A);                                   // out=A
        mlp_fused_k<2><<<2048, 256, 0, stream>>>(A, wl + 393216, mlp_b1 + l * 512,
                                                 wl + 524288, 512, mlp_b2 + l * 256,
                                                 A, h);                                 // y3->h + stats
        affine_k<<<1, 256, 0, stream>>>(bn3_g + l * 256, bn3_b + l * 256, 2);
        // (bn3 affine applied lazily: next layer's aggr, or pool for the last layer)
    }

    pool_k<<<N_GRAPHS_, 256, 0, stream>>>(h, pooled);
    head_k<<<N_GRAPHS_, 128, 0, stream>>>(pooled, head_w1, head_b1, head_w2, head_b2,
                                          head_w3, head_b3, (float*)d_out);
}

// Round 17
// 5011.078 us; speedup vs baseline: 1.0446x; 1.0073x over previous
//
#include <hip/hip_runtime.h>

#define N_NODES 131072
#define N_EDGES 524288
#define CCH 256
#define N_GRAPHS_ 2048
#define SEQ 64
#define LAYERS 6

typedef unsigned short US;
typedef __attribute__((ext_vector_type(8))) short v8s;           // MFMA bf16 frag
typedef __attribute__((ext_vector_type(8))) unsigned short v8us; // 16B ushort vector
typedef __attribute__((ext_vector_type(4))) float v4f;           // MFMA f32 acc

__device__ __forceinline__ float b2f(US u) { return __uint_as_float(((unsigned)u) << 16); }
__device__ __forceinline__ US f2b(float f) {
    unsigned u = __float_as_uint(f);
    return (US)((u + 0x7fff + ((u >> 16) & 1)) >> 16);   // RNE
}
__device__ __forceinline__ void gload16(const US* g, US* l) {
    __builtin_amdgcn_global_load_lds(
        (const __attribute__((address_space(1))) unsigned int*)g,
        (__attribute__((address_space(3))) unsigned int*)l, 16, 0, 0);
}

// cross-kernel state — referenced ONLY inside device code (never from host!)
__device__ float g_stats[512];
__device__ float g_aff1[512];
__device__ float g_aff2[512];
__device__ float g_aff3[512];
__device__ float g_pe[40];
__device__ float g_peaff[40];
__device__ US    g_wt[6 * 655360];          // per-layer transposed bf16 weights
__device__ int   g_csr[N_EDGES];            // per-graph dst-sorted edges: srcLocal | attr<<6
__device__ int   g_off[N_GRAPHS_ * 65];     // per-graph CSR offsets

// ---------------------------------------------------------------- weight transpose f32[K][C] -> bf16[C][K]
__global__ __launch_bounds__(256) void wt_k(const float* __restrict__ cw1, const float* __restrict__ cw2,
                                            const float* __restrict__ aiw, const float* __restrict__ aow,
                                            const float* __restrict__ mw1, const float* __restrict__ mw2) {
    __shared__ float t[64][65];
    int b = blockIdx.x;
    int l = b / 160, r = b % 160;
    const float* src; int ldw, ldk, ctiles; size_t doff;
    if (r < 16)      { src = cw1 + (size_t)l * 65536;  ldw = 256; ldk = 256; ctiles = 4;  doff = 0;      }
    else if (r < 32) { src = cw2 + (size_t)l * 65536;  ldw = 256; ldk = 256; ctiles = 4;  doff = 65536;  r -= 16; }
    else if (r < 80) { src = aiw + (size_t)l * 196608; ldw = 768; ldk = 256; ctiles = 12; doff = 131072; r -= 32; }
    else if (r < 96) { src = aow + (size_t)l * 65536;  ldw = 256; ldk = 256; ctiles = 4;  doff = 327680; r -= 80; }
    else if (r < 128){ src = mw1 + (size_t)l * 131072; ldw = 512; ldk = 256; ctiles = 8;  doff = 393216; r -= 96; }
    else             { src = mw2 + (size_t)l * 131072; ldw = 256; ldk = 512; ctiles = 4;  doff = 524288; r -= 128; }
    int kt = r / ctiles, ct = r % ctiles;
    int k0 = kt * 64, c0 = ct * 64;
    US* dst = g_wt + (size_t)l * 655360 + doff;
    int tid = threadIdx.x;
    int rr = tid >> 4, c4 = (tid & 15) * 4;
    #pragma unroll
    for (int j = 0; j < 4; j++) {
        float4 v = *(const float4*)(src + (size_t)(k0 + rr + j * 16) * ldw + c0 + c4);
        t[rr + j * 16][c4 + 0] = v.x; t[rr + j * 16][c4 + 1] = v.y;
        t[rr + j * 16][c4 + 2] = v.z; t[rr + j * 16][c4 + 3] = v.w;
    }
    __syncthreads();
    #pragma unroll
    for (int j = 0; j < 4; j++) {
        int crow = rr + j * 16;
        ushort4 o;
        o.x = f2b(t[c4 + 0][crow]); o.y = f2b(t[c4 + 1][crow]);
        o.z = f2b(t[c4 + 2][crow]); o.w = f2b(t[c4 + 3][crow]);
        *(ushort4*)(dst + (size_t)(c0 + crow) * ldk + k0 + c4) = o;
    }
}

// ---------------------------------------------------------------- CSR build (once per launch)
__global__ __launch_bounds__(256) void csr_k(const int* __restrict__ ei,
                                             const int* __restrict__ attr) {
    __shared__ int deg[64], off[65];
    int g = blockIdx.x, tid = threadIdx.x;
    if (tid < 64) deg[tid] = 0;
    __syncthreads();
    int e = g * 256 + tid;
    int d = ei[N_EDGES + e] - g * 64;
    int slot = atomicAdd(&deg[d], 1);
    __syncthreads();
    if (tid == 0) {
        off[0] = 0;
        for (int i = 0; i < 64; i++) off[i + 1] = off[i] + deg[i];
    }
    __syncthreads();
    g_csr[g * 256 + off[d] + slot] = (ei[e] - g * 64) | (attr[e] << 6);
    if (tid < 65) g_off[g * 65 + tid] = off[tid];
}

// ---------------------------------------------------------------- pe stats (2-stage)
__global__ __launch_bounds__(256) void pe_part_k(const float* __restrict__ pe) {
    __shared__ float red[240], red2[240];
    int b = blockIdx.x, tid = threadIdx.x;
    float s = 0.f, s2 = 0.f;
    if (tid < 240) {
        int ch = tid % 20, sub = tid / 20;
        size_t r0 = (size_t)b * 512;
        for (int r = sub; r < 512; r += 12) {
            float v = pe[(r0 + r) * 20 + ch];
            s += v; s2 += v * v;
        }
        red[tid] = s; red2[tid] = s2;
    }
    __syncthreads();
    if (tid < 20) {
        float ts = 0.f, ts2 = 0.f;
        #pragma unroll
        for (int sub = 0; sub < 12; sub++) { ts += red[sub * 20 + tid]; ts2 += red2[sub * 20 + tid]; }
        atomicAdd(&g_pe[tid], ts);
        atomicAdd(&g_pe[20 + tid], ts2);
    }
}

__global__ __launch_bounds__(64) void pe_fin_k(const float* __restrict__ g,
                                               const float* __restrict__ b) {
    int t = threadIdx.x;
    if (t < 20) {
        float mean = g_pe[t] / (float)N_NODES;
        float var  = g_pe[20 + t] / (float)N_NODES - mean * mean;
        float a = g[t] * rsqrtf(var + 1e-5f);
        g_peaff[t] = a;
        g_peaff[20 + t] = b[t] - mean * a;
        g_pe[t] = 0.f;          // re-zero for deterministic replay
        g_pe[20 + t] = 0.f;
    }
}

// ---------------------------------------------------------------- embed
__global__ __launch_bounds__(256) void embed_k(const int* __restrict__ x,
                                               const float* __restrict__ pe,
                                               const float* __restrict__ node_emb,
                                               const float* __restrict__ plw,
                                               const float* __restrict__ plb,
                                               US* __restrict__ h) {
    int n = blockIdx.x;
    int tid = threadIdx.x;
    int xi = x[n];
    float v;
    if (tid < 192) {
        v = node_emb[xi * 192 + tid];
    } else {
        int j = tid - 192;
        float s = plb[j];
        #pragma unroll
        for (int k = 0; k < 20; k++) {
            float p = pe[(size_t)n * 20 + k] * g_peaff[k] + g_peaff[20 + k];
            s += p * plw[k * 64 + j];
        }
        v = s;
    }
    h[(size_t)n * CCH + tid] = f2b(v);
}

// ---------------------------------------------------------------- apply bn3 affine (h normalized in place)
__global__ __launch_bounds__(256) void apply_k(US* __restrict__ h) {
    size_t idx = (size_t)blockIdx.x * 256 + threadIdx.x;
    size_t stride = (size_t)gridDim.x * 256;
    for (; idx < (size_t)N_NODES * CCH / 8; idx += stride) {
        size_t i = idx * 8;
        int c = (int)(i & 255);
        v8us a = *(const v8us*)(h + i);
        v8us o;
        #pragma unroll
        for (int j = 0; j < 8; j++)
            o[j] = f2b(b2f(a[j]) * g_aff3[c + j] + g_aff3[CCH + c + j]);
        *(v8us*)(h + i) = o;
    }
}

// ---------------------------------------------------------------- edge aggregation: CSR, no atomics
__global__ __launch_bounds__(256) void aggr_z_k(const US* __restrict__ h,
                                                const float* __restrict__ eemb,
                                                US* __restrict__ z) {
    __shared__ US ht[64 * 264];
    __shared__ float em[4 * 260];
    __shared__ int off[65], ce[256];
    int g = blockIdx.x, tid = threadIdx.x;
    for (int v = tid; v < 2048; v += 256) {
        int row = v >> 5, seg = (v & 31) * 8;
        *(v8us*)&ht[row * 264 + seg] = *(const v8us*)(h + (size_t)(g * 64 + row) * 256 + seg);
    }
    for (int i = tid; i < 1024; i += 256)
        em[(i >> 8) * 260 + (i & 255)] = eemb[(i >> 8) * 256 + (i & 255)];
    ce[tid] = g_csr[g * 256 + tid];
    if (tid < 65) off[tid] = g_off[g * 65 + tid];
    __syncthreads();

    int dst = tid >> 2, cq = (tid & 3) * 4;
    float acc[64];
    #pragma unroll
    for (int i = 0; i < 64; i++) acc[i] = 0.f;
    int e1 = off[dst + 1];
    for (int e = off[dst]; e < e1; e++) {
        int val = ce[e];
        int src = val & 63, a = (val >> 6) & 3;
        #pragma unroll
        for (int i = 0; i < 16; i++) {
            int c = cq + i * 16;
            ushort4 hv = *(ushort4*)&ht[src * 264 + c];
            float4 ev = *(float4*)&em[a * 260 + c];
            acc[i * 4 + 0] += fmaxf(b2f(hv.x) + ev.x, 0.f);
            acc[i * 4 + 1] += fmaxf(b2f(hv.y) + ev.y, 0.f);
            acc[i * 4 + 2] += fmaxf(b2f(hv.z) + ev.z, 0.f);
            acc[i * 4 + 3] += fmaxf(b2f(hv.w) + ev.w, 0.f);
        }
    }
    US* zp = z + (size_t)(g * 64 + dst) * 256;
    #pragma unroll
    for (int i = 0; i < 16; i++) {
        int c = cq + i * 16;
        ushort4 hv = *(ushort4*)&ht[dst * 264 + c];
        ushort4 o;
        o.x = f2b(b2f(hv.x) + acc[i * 4 + 0]);
        o.y = f2b(b2f(hv.y) + acc[i * 4 + 1]);
        o.z = f2b(b2f(hv.z) + acc[i * 4 + 2]);
        o.w = f2b(b2f(hv.w) + acc[i * 4 + 3]);
        *(ushort4*)(zp + c) = o;
    }
}

// ---------------------------------------------------------------- MFMA bf16 GEMM  (BM=64, EXACT round-10 version)
template<int NG, bool STATS>
__global__ __launch_bounds__(256, 4) void gemm_mfma_k(const US* __restrict__ A,
                                                      size_t woff, int ldk,
                                                      int w0, int w1, int w2, int w3,
                                                      const float* __restrict__ bias,
                                                      const US* __restrict__ res,
                                                      US* __restrict__ Y, int mode) {
    const US* __restrict__ Wt = g_wt + woff;
    __shared__ __align__(16) char smem[8192 + 2 * NG * 4096];
    US* As0 = (US*)smem;
    US* As1 = As0 + 2048;
    US* Bs0 = (US*)(smem + 8192);
    US* Bs1 = Bs0 + NG * 2048;
    float* Es = (float*)smem;
    const int NW = NG * 64 + 4;

    int tid = threadIdx.x;
    int bid = blockIdx.x;
    int swz = (bid & 7) * ((int)gridDim.x >> 3) + (bid >> 3);
    size_t row0 = (size_t)swz * 64;
    int w = tid >> 6, l = tid & 63;
    int li = l & 15, hi = l >> 4;
    int sl = hi ^ ((li >> 1) & 3);
    int sr = l >> 2, ss = l & 3;

    int a_off = (w * 16 + li) * 32 + sl * 8;

    v4f acc[NG * 4];
    #pragma unroll
    for (int t = 0; t < NG * 4; t++) acc[t] = (v4f){0.f, 0.f, 0.f, 0.f};

    int ar = w * 16 + sr;
    int akg = (ss ^ ((ar >> 1) & 3)) * 8;
    const US* asrc = A + (row0 + ar) * 256 + akg;

    auto stage = [&](int kc, US* Asb, US* Bsb) {
        int k0 = kc * 32;
        gload16(asrc + k0, Asb + w * 512);
        #pragma unroll
        for (int j = 0; j < NG; j++) {
            int cu = (j * 4 + w) * 16 + sr;
            int grp = cu >> 6;
            int wb = (grp == 0) ? w0 : (grp == 1) ? w1 : (grp == 2) ? w2 : w3;
            int kg = (ss ^ ((cu >> 1) & 3)) * 8;
            gload16(Wt + (size_t)(wb + (cu & 63)) * ldk + k0 + kg,
                    Bsb + (j * 4 + w) * 512);
        }
    };

    stage(0, As0, Bs0);
    __syncthreads();
    for (int kc = 0; kc < 8; kc++) {
        US* Asc = (kc & 1) ? As1 : As0;
        US* Bsc = (kc & 1) ? Bs1 : Bs0;
        if (kc < 7) stage(kc + 1, (kc & 1) ? As0 : As1, (kc & 1) ? Bs0 : Bs1);
        v8s a0 = *(v8s*)(Asc + a_off);
        #pragma unroll
        for (int t = 0; t < NG * 4; t++) {
            v8s bf = *(v8s*)(Bsc + (t * 16 + li) * 32 + sl * 8);
            acc[t] = __builtin_amdgcn_mfma_f32_16x16x32_bf16(a0, bf, acc[t], 0, 0, 0);
        }
        __syncthreads();
    }

    int er_f = tid >> 3;
    int lcb = (tid & 7) * 8;
    float csum = 0.f, csum2 = 0.f;
    #pragma unroll
    for (int p = 0; p < 2; p++) {
        if ((w >> 1) == p) {
            int er0 = (w & 1) * 16 + hi * 4;
            #pragma unroll
            for (int t = 0; t < NG * 4; t++) {
                int grp = t >> 2;
                int wb = (grp == 0) ? w0 : (grp == 1) ? w1 : (grp == 2) ? w2 : w3;
                float bv = bias ? bias[wb + (t & 3) * 16 + li] : 0.f;
                #pragma unroll
                for (int r = 0; r < 4; r++) {
                    float v = acc[t][r] + bv;
                    if (mode == 1) v = fmaxf(v, 0.f);
                    Es[(er0 + r) * NW + t * 16 + li] = v;
                }
            }
        }
        __syncthreads();
        size_t gr = row0 + p * 32 + er_f;
        #pragma unroll
        for (int s = 0; s < NG; s++) {
            int c = s * 64 + lcb;
            float vs[8];
            #pragma unroll
            for (int j = 0; j < 8; j++) vs[j] = Es[er_f * NW + c + j];
            if (mode == 2) {
                v8us rv = *(const v8us*)(res + gr * 256 + c);
                #pragma unroll
                for (int j = 0; j < 8; j++) vs[j] += b2f(rv[j]);
            }
            v8us yv;
            #pragma unroll
            for (int j = 0; j < 8; j++) yv[j] = f2b(vs[j]);
            *(v8us*)(Y + gr * 256 + c) = yv;
            if constexpr (STATS) {
                #pragma unroll
                for (int j = 0; j < 8; j++) Es[er_f * NW + c + j] = vs[j];
            }
        }
        if constexpr (STATS) {
            __syncthreads();
            if (tid < NG * 64) {
                float s1 = 0.f, s2 = 0.f;
                #pragma unroll 8
                for (int r2 = 0; r2 < 32; r2++) {
                    float vv = Es[r2 * NW + tid];
                    s1 += vv; s2 += vv * vv;
                }
                csum += s1; csum2 += s2;
            }
        }
        __syncthreads();
    }
    if constexpr (STATS) {
        if (tid < NG * 64) {
            atomicAdd(&g_stats[tid], csum);
            atomicAdd(&g_stats[CCH + tid], csum2);
        }
    }
}

// ---------------------------------------------------------------- FUSED chained GEMM: Y = relu(A@W1+b1)@W2 + b2 + res
// EXACT round-14 version (gload_lds staging). NH 256-wide t-chunks. Safe for Y == A (block-local).
template<int NH>
__global__ __launch_bounds__(256, 2) void mlp_fused_k(const US* __restrict__ A,
                                                      size_t woff1, const float* __restrict__ bias1,
                                                      size_t woff2, int ldk2,
                                                      const float* __restrict__ bias2,
                                                      const US* __restrict__ res,
                                                      US* __restrict__ Y) {
    const US* __restrict__ W1t = g_wt + woff1;
    const US* __restrict__ W2t = g_wt + woff2;
    __shared__ __align__(16) char smem[73728];
    US* As0 = (US*)smem;
    US* As1 = (US*)(smem + 4096);
    US* Bs0 = (US*)(smem + 8192);
    US* Bs1 = (US*)(smem + 24576);
    float* Es = (float*)smem;
    US* Ts = (US*)(smem + 40960);

    int tid = threadIdx.x;
    int bid = blockIdx.x;
    int swz = (bid & 7) * ((int)gridDim.x >> 3) + (bid >> 3);
    size_t row0 = (size_t)swz * 64;
    int w = tid >> 6, l = tid & 63;
    int li = l & 15, hi = l >> 4;
    int sl = hi ^ ((li >> 1) & 3);
    int sr = l >> 2, ss = l & 3;

    int a_off = (w * 16 + li) * 32 + sl * 8;

    v4f accY[16];
    #pragma unroll
    for (int t = 0; t < 16; t++) accY[t] = (v4f){0.f, 0.f, 0.f, 0.f};

    int ar = w * 16 + sr;
    int akg = (ss ^ ((ar >> 1) & 3)) * 8;
    const US* asrc = A + (row0 + ar) * 256 + akg;

    #pragma unroll
    for (int q = 0; q < NH; q++) {
        v4f accT[16];
        #pragma unroll
        for (int t = 0; t < 16; t++) accT[t] = (v4f){0.f, 0.f, 0.f, 0.f};

        auto stageA = [&](int kc, US* Asb, US* Bsb) {
            int k0 = kc * 32;
            gload16(asrc + k0, Asb + w * 512);
            #pragma unroll
            for (int j = 0; j < 4; j++) {
                int cu = (j * 4 + w) * 16 + sr;
                int kg = (ss ^ ((cu >> 1) & 3)) * 8;
                gload16(W1t + (size_t)(q * 256 + cu) * 256 + k0 + kg,
                        Bsb + (j * 4 + w) * 512);
            }
        };
        stageA(0, As0, Bs0);
        __syncthreads();
        for (int kc = 0; kc < 8; kc++) {
            US* Asc = (kc & 1) ? As1 : As0;
            US* Bsc = (kc & 1) ? Bs1 : Bs0;
            if (kc < 7) stageA(kc + 1, (kc & 1) ? As0 : As1, (kc & 1) ? Bs0 : Bs1);
            v8s a0 = *(v8s*)(Asc + a_off);
            #pragma unroll
            for (int t = 0; t < 16; t++) {
                v8s bf = *(v8s*)(Bsc + (t * 16 + li) * 32 + sl * 8);
                accT[t] = __builtin_amdgcn_mfma_f32_16x16x32_bf16(a0, bf, accT[t], 0, 0, 0);
            }
            __syncthreads();
        }
        // ---- t -> Ts via Es transpose (bias + relu + bf16 round) ----
        #pragma unroll
        for (int p = 0; p < 2; p++) {
            if ((w >> 1) == p) {
                int er0 = (w & 1) * 16 + hi * 4;
                #pragma unroll
                for (int t = 0; t < 16; t++) {
                    float bv = bias1[q * 256 + t * 16 + li];
                    #pragma unroll
                    for (int r = 0; r < 4; r++)
                        Es[(er0 + r) * 260 + t * 16 + li] = fmaxf(accT[t][r] + bv, 0.f);
                }
            }
            __syncthreads();
            {
                int er = tid >> 3, lcb = (tid & 7) * 8;
                int rowL = p * 32 + er;
                int rsw = (rowL >> 1) & 3;
                #pragma unroll
                for (int s = 0; s < 4; s++) {
                    int col = s * 64 + lcb;
                    v8us tv;
                    #pragma unroll
                    for (int j = 0; j < 8; j++) tv[j] = f2b(Es[er * 260 + col + j]);
                    int chunk = col >> 5, slot = ((col >> 3) & 3) ^ rsw;
                    *(v8us*)&Ts[chunk * 2048 + rowL * 32 + slot * 8] = tv;
                }
            }
            __syncthreads();
        }
        // ---- phase B: accY += t @ W2[q*256 + k][:] ----
        auto stageB = [&](int kc, US* Bsb) {
            int k0 = q * 256 + kc * 32;
            #pragma unroll
            for (int j = 0; j < 4; j++) {
                int cu = (j * 4 + w) * 16 + sr;
                int kg = (ss ^ ((cu >> 1) & 3)) * 8;
                gload16(W2t + (size_t)cu * ldk2 + k0 + kg, Bsb + (j * 4 + w) * 512);
            }
        };
        stageB(0, Bs0);
        __syncthreads();
        for (int kc = 0; kc < 8; kc++) {
            US* Bsc = (kc & 1) ? Bs1 : Bs0;
            if (kc < 7) stageB(kc + 1, (kc & 1) ? Bs0 : Bs1);
            v8s a0 = *(v8s*)(Ts + kc * 2048 + a_off);
            #pragma unroll
            for (int t = 0; t < 16; t++) {
                v8s bf = *(v8s*)(Bsc + (t * 16 + li) * 32 + sl * 8);
                accY[t] = __builtin_amdgcn_mfma_f32_16x16x32_bf16(a0, bf, accY[t], 0, 0, 0);
            }
            __syncthreads();
        }
    }

    // ---- final epilogue: bias2 + res + stats -> Y ----
    int er_f = tid >> 3;
    int lcb = (tid & 7) * 8;
    float csum = 0.f, csum2 = 0.f;
    #pragma unroll
    for (int p = 0; p < 2; p++) {
        if ((w >> 1) == p) {
            int er0 = (w & 1) * 16 + hi * 4;
            #pragma unroll
            for (int t = 0; t < 16; t++) {
                float bv = bias2[t * 16 + li];
                #pragma unroll
                for (int r = 0; r < 4; r++)
                    Es[(er0 + r) * 260 + t * 16 + li] = accY[t][r] + bv;
            }
        }
        __syncthreads();
        size_t gr = row0 + p * 32 + er_f;
        #pragma unroll
        for (int s = 0; s < 4; s++) {
            int c = s * 64 + lcb;
            float vs[8];
            #pragma unroll
            for (int j = 0; j < 8; j++) vs[j] = Es[er_f * 260 + c + j];
            v8us rv = *(const v8us*)(res + gr * 256 + c);
            #pragma unroll
            for (int j = 0; j < 8; j++) vs[j] += b2f(rv[j]);
            v8us yv;
            #pragma unroll
            for (int j = 0; j < 8; j++) yv[j] = f2b(vs[j]);
            *(v8us*)(Y + gr * 256 + c) = yv;
            #pragma unroll
            for (int j = 0; j < 8; j++) Es[er_f * 260 + c + j] = vs[j];
        }
        __syncthreads();
        {
            float s1 = 0.f, s2 = 0.f;
            #pragma unroll 8
            for (int r2 = 0; r2 < 32; r2++) {
                float vv = Es[r2 * 260 + tid];
                s1 += vv; s2 += vv * vv;
            }
            csum += s1; csum2 += s2;
        }
        __syncthreads();
    }
    atomicAdd(&g_stats[tid], csum);
    atomicAdd(&g_stats[CCH + tid], csum2);
}

// ---------------------------------------------------------------- MFMA attention: grid (2048,4); 1 wave = (graph, head)
// q from qb cols hh*64, k from kb, v from vb; o written IN PLACE to qb cols hh*64.
__global__ __launch_bounds__(64) void attn_k(US* __restrict__ qb,
                                             const US* __restrict__ kb,
                                             const US* __restrict__ vb) {
    __shared__ __align__(16) US Ps[64 * 72];
    __shared__ __align__(16) US Vt[64 * 72];
    int g = blockIdx.x, l = threadIdx.x;
    int coff = blockIdx.y * 64;
    int li = l & 15, hi8 = (l >> 4) * 8, hi4 = (l >> 4) * 4;
    size_t rb = (size_t)g * 64 * 256;

    {
        v8us vv[8];
        #pragma unroll
        for (int jv = 0; jv < 8; jv++)
            vv[jv] = *(const v8us*)(vb + rb + l * 256 + coff + jv * 8);
        #pragma unroll
        for (int jv = 0; jv < 8; jv++)
            #pragma unroll
            for (int e = 0; e < 8; e++)
                Vt[(jv * 8 + e) * 72 + l] = vv[jv][e];
    }

    v8s Qf[4][2], Kf[4][2];
    #pragma unroll
    for (int t = 0; t < 4; t++)
        #pragma unroll
        for (int ds = 0; ds < 2; ds++) {
            Qf[t][ds] = *(const v8s*)(qb + rb + (t * 16 + li) * 256 + coff + ds * 32 + hi8);
            Kf[t][ds] = *(const v8s*)(kb + rb + (t * 16 + li) * 256 + coff + ds * 32 + hi8);
        }

    v4f S[4][4];
    #pragma unroll
    for (int qt = 0; qt < 4; qt++)
        #pragma unroll
        for (int kt = 0; kt < 4; kt++) {
            v4f a = (v4f){0.f, 0.f, 0.f, 0.f};
            a = __builtin_amdgcn_mfma_f32_16x16x32_bf16(Qf[qt][0], Kf[kt][0], a, 0, 0, 0);
            a = __builtin_amdgcn_mfma_f32_16x16x32_bf16(Qf[qt][1], Kf[kt][1], a, 0, 0, 0);
            S[qt][kt] = a;
        }

    #pragma unroll
    for (int qt = 0; qt < 4; qt++)
        #pragma unroll
        for (int r = 0; r < 4; r++) {
            float mx = -1e30f;
            #pragma unroll
            for (int kt = 0; kt < 4; kt++) {
                S[qt][kt][r] *= 0.125f;
                mx = fmaxf(mx, S[qt][kt][r]);
            }
            mx = fmaxf(mx, __shfl_xor(mx, 1));
            mx = fmaxf(mx, __shfl_xor(mx, 2));
            mx = fmaxf(mx, __shfl_xor(mx, 4));
            mx = fmaxf(mx, __shfl_xor(mx, 8));
            float sum = 0.f;
            #pragma unroll
            for (int kt = 0; kt < 4; kt++) {
                float e = __expf(S[qt][kt][r] - mx);
                S[qt][kt][r] = e;
                sum += e;
            }
            sum += __shfl_xor(sum, 1);
            sum += __shfl_xor(sum, 2);
            sum += __shfl_xor(sum, 4);
            sum += __shfl_xor(sum, 8);
            float inv = 1.f / sum;
            #pragma unroll
            for (int kt = 0; kt < 4; kt++)
                Ps[(qt * 16 + hi4 + r) * 72 + kt * 16 + li] = f2b(S[qt][kt][r] * inv);
        }

    v4f O[4][4];
    #pragma unroll
    for (int qt = 0; qt < 4; qt++)
        #pragma unroll
        for (int jt = 0; jt < 4; jt++) O[qt][jt] = (v4f){0.f, 0.f, 0.f, 0.f};
    #pragma unroll
    for (int ks = 0; ks < 2; ks++) {
        v8s Pf[4], Vf[4];
        #pragma unroll
        for (int qt = 0; qt < 4; qt++)
            Pf[qt] = *(v8s*)&Ps[(qt * 16 + li) * 72 + ks * 32 + hi8];
        #pragma unroll
        for (int jt = 0; jt < 4; jt++)
            Vf[jt] = *(v8s*)&Vt[(jt * 16 + li) * 72 + ks * 32 + hi8];
        #pragma unroll
        for (int qt = 0; qt < 4; qt++)
            #pragma unroll
            for (int jt = 0; jt < 4; jt++)
                O[qt][jt] = __builtin_amdgcn_mfma_f32_16x16x32_bf16(Pf[qt], Vf[jt], O[qt][jt], 0, 0, 0);
    }

    __syncthreads();                   // Ps fully consumed before reuse as O
    #pragma unroll
    for (int qt = 0; qt < 4; qt++)
        #pragma unroll
        for (int jt = 0; jt < 4; jt++)
            #pragma unroll
            for (int r = 0; r < 4; r++)
                Ps[(qt * 16 + hi4 + r) * 72 + jt * 16 + li] = f2b(O[qt][jt][r]);
    __syncthreads();
    US* ob = qb + rb + l * 256 + coff;   // overwrite dead q columns
    #pragma unroll
    for (int jv = 0; jv < 8; jv++)
        *(v8us*)(ob + jv * 8) = *(v8us*)&Ps[l * 72 + jv * 8];
}

// ---------------------------------------------------------------- BN affine (stats fused into GEMM epilogue)
__global__ __launch_bounds__(256) void affine_k(const float* __restrict__ g,
                                                const float* __restrict__ b, int sel) {
    int c = threadIdx.x;
    float mean = g_stats[c] / (float)N_NODES;
    float var  = g_stats[CCH + c] / (float)N_NODES - mean * mean;
    float a = g[c] * rsqrtf(var + 1e-5f);
    float* dst = (sel == 0) ? g_aff1 : (sel == 1) ? g_aff2 : g_aff3;
    dst[c] = a;
    dst[CCH + c] = b[c] - mean * a;
    g_stats[c] = 0.f;
    g_stats[CCH + c] = 0.f;
}

// ---------------------------------------------------------------- combine (v8us vectorized)
__global__ __launch_bounds__(256) void combine_k(const US* __restrict__ y1,
                                                 const US* __restrict__ y2,
                                                 US* __restrict__ out) {
    size_t idx = (size_t)blockIdx.x * 256 + threadIdx.x;
    size_t stride = (size_t)gridDim.x * 256;
    for (; idx < (size_t)N_NODES * CCH / 8; idx += stride) {
        size_t i = idx * 8;
        int c = (int)(i & 255);
        v8us a = *(const v8us*)(y1 + i);
        v8us b = *(const v8us*)(y2 + i);
        v8us o;
        #pragma unroll
        for (int j = 0; j < 8; j++) {
            float v = b2f(a[j]) * g_aff1[c + j] + g_aff1[CCH + c + j] +
                      b2f(b[j]) * g_aff2[c + j] + g_aff2[CCH + c + j];
            o[j] = f2b(v);
        }
        *(v8us*)(out + i) = o;
    }
}

// ---------------------------------------------------------------- pool (applies aff3 analytically) + head
__global__ __launch_bounds__(256) void pool_k(const US* __restrict__ h,
                                              float* __restrict__ pooled) {
    int g = blockIdx.x, c = threadIdx.x;
    float s = 0.f;
    for (int ss = 0; ss < SEQ; ss++) s += b2f(h[((size_t)g * SEQ + ss) * CCH + c]);
    pooled[(size_t)g * CCH + c] = g_aff3[c] * s + 64.f * g_aff3[CCH + c];
}

__global__ __launch_bounds__(128) void head_k(const float* __restrict__ pooled,
                                              const float* __restrict__ w1, const float* __restrict__ b1,
                                              const float* __restrict__ w2, const float* __restrict__ b2,
                                              const float* __restrict__ w3, const float* __restrict__ b3,
                                              float* __restrict__ outp) {
    __shared__ float p[256], t1[128], t2[64];
    int g = blockIdx.x, tid = threadIdx.x;
    p[tid] = pooled[(size_t)g * CCH + tid];
    p[tid + 128] = pooled[(size_t)g * CCH + 128 + tid];
    __syncthreads();
    float s = b1[tid];
    for (int k = 0; k < 256; k++) s += p[k] * w1[k * 128 + tid];
    t1[tid] = fmaxf(s, 0.f);
    __syncthreads();
    if (tid < 64) {
        float s2 = b2[tid];
        for (int k = 0; k < 128; k++) s2 += t1[k] * w2[k * 64 + tid];
        t2[tid] = fmaxf(s2, 0.f);
    }
    __syncthreads();
    if (tid == 0) {
        float s3 = b3[0];
        for (int k = 0; k < 64; k++) s3 += t2[k] * w3[k];
        outp[g] = s3;
    }
}

// ================================================================ launch
extern "C" void kernel_launch(void* const* d_in, const int* in_sizes, int n_in,
                              void* d_out, int out_size, void* d_ws, size_t ws_size,
                              hipStream_t stream) {
    const int*   x         = (const int*)  d_in[0];
    const float* pe        = (const float*)d_in[1];
    const int*   ei        = (const int*)  d_in[2];
    const int*   eattr     = (const int*)  d_in[3];
    const float* node_emb  = (const float*)d_in[5];
    const float* pe_lin_w  = (const float*)d_in[6];
    const float* pe_lin_b  = (const float*)d_in[7];
    const float* pe_norm_g = (const float*)d_in[8];
    const float* pe_norm_b = (const float*)d_in[9];
    const float* edge_emb  = (const float*)d_in[10];
    const float* conv_w1   = (const float*)d_in[11];
    const float* conv_b1   = (const float*)d_in[12];
    const float* conv_w2   = (const float*)d_in[13];
    const float* conv_b2   = (const float*)d_in[14];
    const float* attn_in_w = (const float*)d_in[15];
    const float* attn_in_b = (const float*)d_in[16];
    const float* attn_out_w= (const float*)d_in[17];
    const float* attn_out_b= (const float*)d_in[18];
    const float* bn1_g     = (const float*)d_in[19];
    const float* bn1_b     = (const float*)d_in[20];
    const float* bn2_g     = (const float*)d_in[21];
    const float* bn2_b     = (const float*)d_in[22];
    const float* bn3_g     = (const float*)d_in[23];
    const float* bn3_b     = (const float*)d_in[24];
    const float* mlp_w1    = (const float*)d_in[25];
    const float* mlp_b1    = (const float*)d_in[26];
    const float* mlp_w2    = (const float*)d_in[27];
    const float* mlp_b2    = (const float*)d_in[28];
    const float* head_w1   = (const float*)d_in[29];
    const float* head_b1   = (const float*)d_in[30];
    const float* head_w2   = (const float*)d_in[31];
    const float* head_b2   = (const float*)d_in[32];
    const float* head_w3   = (const float*)d_in[33];
    const float* head_b3   = (const float*)d_in[34];
    (void)in_sizes; (void)n_in; (void)out_size; (void)ws_size;

    // workspace: 4 x 64 MB bf16 [N,256] buffers = 256 MB total (proven safe)
    char* ws = (char*)d_ws;
    US* h = (US*)(ws);
    US* A = (US*)(ws + 67108864ULL);
    US* B = (US*)(ws + 134217728ULL);
    US* C = (US*)(ws + 201326592ULL);
    float* pooled = (float*)(ws + 67108864ULL);   // reuses A (dead after layer loop)

    wt_k<<<960, 256, 0, stream>>>(conv_w1, conv_w2, attn_in_w, attn_out_w, mlp_w1, mlp_w2);
    csr_k<<<N_GRAPHS_, 256, 0, stream>>>(ei, eattr);
    pe_part_k<<<256, 256, 0, stream>>>(pe);
    pe_fin_k<<<1, 64, 0, stream>>>(pe_norm_g, pe_norm_b);
    embed_k<<<N_NODES, 256, 0, stream>>>(x, pe, node_emb, pe_lin_w, pe_lin_b, h);

    for (int l = 0; l < LAYERS; l++) {
        size_t wl = (size_t)l * 655360;

        // ---- normalize h with prev layer's bn3 affine ----
        if (l > 0) apply_k<<<2048, 256, 0, stream>>>(h);

        // ---- global attention: q->A, k->B, v->C (full width), one attn launch, o->A ----
        gemm_mfma_k<4, false><<<2048, 256, 0, stream>>>(h, wl + 131072, 256, 0, 64, 128, 192,
                                                        attn_in_b + l * 768, nullptr, A, 0);  // q
        gemm_mfma_k<4, false><<<2048, 256, 0, stream>>>(h, wl + 131072, 256, 256, 320, 384, 448,
                                                        attn_in_b + l * 768, nullptr, B, 0);  // k
        gemm_mfma_k<4, false><<<2048, 256, 0, stream>>>(h, wl + 131072, 256, 512, 576, 640, 704,
                                                        attn_in_b + l * 768, nullptr, C, 0);  // v
        attn_k<<<dim3(N_GRAPHS_, 4), 64, 0, stream>>>(A, B, C);                               // o->A
        gemm_mfma_k<4, true><<<2048, 256, 0, stream>>>(A, wl + 327680, 256, 0, 64, 128, 192,
                                                       attn_out_b + l * 256, h, B, 2);        // y2->B + stats
        affine_k<<<1, 256, 0, stream>>>(bn2_g + l * 256, bn2_b + l * 256, 1);

        // ---- local GINEConv ----
        aggr_z_k<<<N_GRAPHS_, 256, 0, stream>>>(h, edge_emb, C);                              // z->C
        mlp_fused_k<1><<<2048, 256, 0, stream>>>(C, wl, conv_b1 + l * 256,
                                                 wl + 65536, 256, conv_b2 + l * 256,
                                                 h, C);                                       // y1->C (in place) + stats
        affine_k<<<1, 256, 0, stream>>>(bn1_g + l * 256, bn1_b + l * 256, 0);

        // ---- combine + fused FFN ----
        combine_k<<<2048, 256, 0, stream>>>(C, B, A);                                         // out->A
        mlp_fused_k<2><<<2048, 256, 0, stream>>>(A, wl + 393216, mlp_b1 + l * 512,
                                                 wl + 524288, 512, mlp_b2 + l * 256,
                                                 A, h);                                       // y3->h + stats
        affine_k<<<1, 256, 0, stream>>>(bn3_g + l * 256, bn3_b + l * 256, 2);
        // (bn3 affine applied lazily: next layer's apply_k, or pool for the last layer)
    }

    pool_k<<<N_GRAPHS_, 256, 0, stream>>>(h, pooled);
    head_k<<<N_GRAPHS_, 128, 0, stream>>>(pooled, head_w1, head_b1, head_w2, head_b2,
                                          head_w3, head_b3, (float*)d_out);
}